// Round 1
// baseline (1862.873 us; speedup 1.0000x reference)
//
#include <hip/hip_runtime.h>
#include <hip/hip_bf16.h>
#include <math.h>

// Problem constants
#define Bb 4
#define Ss 4096
#define Dd 1024
#define Hh 16
#define DKk 64
#define Mm (Bb * Ss)          // 16384 rows
#define NCH 16                // n-chunks per head for KV partial reduction

// ---------------- GEMM: C[M,D] = act(A[M,K] @ W[N,K]^T + bias) ----------------
// fp32 vector-FMA tiled GEMM. BM=BN=128, BK=16, 256 threads, 8x8 acc/thread.
#define BM 128
#define BN 128
#define BK 16
#define LDSW (BM + 4)   // +4 pad: staging writes become 2-way (free), reads stay aligned

template <int ACT>
__global__ __launch_bounds__(256) void gemm_nt_act(
    const float* __restrict__ A, const float* __restrict__ W,
    const float* __restrict__ bias, float* __restrict__ C) {
  __shared__ float As[BK][LDSW];
  __shared__ float Bs[BK][LDSW];
  const int K = Dd;
  const int bn = blockIdx.x, bm = blockIdx.y;
  const int t = threadIdx.x;
  const int tx = t & 15, ty = t >> 4;
  const int m0 = ty * 8, n0 = tx * 8;
  const int r0 = t >> 2;            // 0..63 (staging row)
  const int kp = (t & 3) << 2;      // 0,4,8,12 (staging k offset)

  const float* Ab = A + (size_t)bm * BM * K;
  const float* Wb = W + (size_t)bn * BN * K;

  float acc[8][8];
#pragma unroll
  for (int i = 0; i < 8; ++i)
#pragma unroll
    for (int j = 0; j < 8; ++j) acc[i][j] = 0.f;

  for (int k0 = 0; k0 < K; k0 += BK) {
    // issue global loads early (overlap with previous tile's compute)
    float4 a0 = *(const float4*)&Ab[(size_t)r0 * K + k0 + kp];
    float4 a1 = *(const float4*)&Ab[(size_t)(r0 + 64) * K + k0 + kp];
    float4 w0 = *(const float4*)&Wb[(size_t)r0 * K + k0 + kp];
    float4 w1 = *(const float4*)&Wb[(size_t)(r0 + 64) * K + k0 + kp];
    __syncthreads();  // WAR: previous compute must finish before overwrite
    As[kp + 0][r0] = a0.x; As[kp + 1][r0] = a0.y; As[kp + 2][r0] = a0.z; As[kp + 3][r0] = a0.w;
    As[kp + 0][r0 + 64] = a1.x; As[kp + 1][r0 + 64] = a1.y; As[kp + 2][r0 + 64] = a1.z; As[kp + 3][r0 + 64] = a1.w;
    Bs[kp + 0][r0] = w0.x; Bs[kp + 1][r0] = w0.y; Bs[kp + 2][r0] = w0.z; Bs[kp + 3][r0] = w0.w;
    Bs[kp + 0][r0 + 64] = w1.x; Bs[kp + 1][r0 + 64] = w1.y; Bs[kp + 2][r0 + 64] = w1.z; Bs[kp + 3][r0 + 64] = w1.w;
    __syncthreads();
#pragma unroll
    for (int kk = 0; kk < BK; ++kk) {
      float a[8], b[8];
      *(float4*)&a[0] = *(const float4*)&As[kk][m0];
      *(float4*)&a[4] = *(const float4*)&As[kk][m0 + 4];
      *(float4*)&b[0] = *(const float4*)&Bs[kk][n0];
      *(float4*)&b[4] = *(const float4*)&Bs[kk][n0 + 4];
#pragma unroll
      for (int i = 0; i < 8; ++i)
#pragma unroll
        for (int j = 0; j < 8; ++j)
          acc[i][j] = fmaf(a[i], b[j], acc[i][j]);
    }
  }

#pragma unroll
  for (int i = 0; i < 8; ++i) {
    const size_t m = (size_t)bm * BM + m0 + i;
#pragma unroll
    for (int j = 0; j < 8; ++j) {
      const int n = bn * BN + n0 + j;
      float v = acc[i][j] + bias[n];
      if (ACT) v = (v > 0.f) ? (v + 1.f) : expf(v);  // elu(x)+1
      C[m * Dd + n] = v;
    }
  }
}

// ------------- KV partial: per (b,h,chunk) block, 256 rows ----------------
// part[bx][m*64+d] = sum_n V[n,m]*K[n,d];  part[bx][4096+d] = sum_n K[n,d]
__global__ __launch_bounds__(256) void kv_partial(
    const float* __restrict__ Kf, const float* __restrict__ Vf,
    float* __restrict__ part) {
  const int bx = blockIdx.x;            // b*H*NCH + h*NCH + chunk
  const int chunk = bx % NCH;
  const int bh = bx / NCH;
  const int h = bh % Hh, b = bh / Hh;
  const int t = threadIdx.x;
  const int tm = t >> 4, td = t & 15;   // thread owns m=tm*4+i, d=td*4+j
  __shared__ float sK[8][64];
  __shared__ float sV[8][64];
  float acc[4][4] = {{0.f}};
  float ksr[4] = {0.f, 0.f, 0.f, 0.f};

  const int which = t >> 7;             // 0: K, 1: V
  const int idx = t & 127;
  const int rr = idx >> 4;              // 0..7
  const int dpos = (idx & 15) << 2;     // 0..60
  const int colbase = h * DKk;
  const int rows = Ss / NCH;            // 256

  for (int n0 = 0; n0 < rows; n0 += 8) {
    const int gr = b * Ss + chunk * rows + n0 + rr;
    const float* src = which ? Vf : Kf;
    float4 v = *(const float4*)&src[(size_t)gr * Dd + colbase + dpos];
    __syncthreads();
    float* dst = which ? &sV[rr][dpos] : &sK[rr][dpos];
    *(float4*)dst = v;
    __syncthreads();
#pragma unroll
    for (int r = 0; r < 8; ++r) {
      float kv[4], vv[4];
#pragma unroll
      for (int j = 0; j < 4; ++j) kv[j] = sK[r][td * 4 + j];
#pragma unroll
      for (int i = 0; i < 4; ++i) vv[i] = sV[r][tm * 4 + i];
#pragma unroll
      for (int i = 0; i < 4; ++i)
#pragma unroll
        for (int j = 0; j < 4; ++j)
          acc[i][j] = fmaf(vv[i], kv[j], acc[i][j]);
      if (tm == 0) {
#pragma unroll
        for (int j = 0; j < 4; ++j) ksr[j] += kv[j];
      }
    }
  }

  float* p = part + (size_t)bx * 4160;
#pragma unroll
  for (int i = 0; i < 4; ++i)
#pragma unroll
    for (int j = 0; j < 4; ++j)
      p[(tm * 4 + i) * 64 + td * 4 + j] = acc[i][j];
  if (tm == 0) {
#pragma unroll
    for (int j = 0; j < 4; ++j) p[4096 + td * 4 + j] = ksr[j];
  }
}

// ------------- KV reduce: sum NCH partials per head ----------------
__global__ __launch_bounds__(256) void kv_reduce(
    const float* __restrict__ part, float* __restrict__ KV,
    float* __restrict__ Ksum) {
  const int bh = blockIdx.x;
  for (int e = threadIdx.x; e < 4160; e += 256) {
    float s = 0.f;
#pragma unroll
    for (int c = 0; c < NCH; ++c)
      s += part[((size_t)bh * NCH + c) * 4160 + e];
    if (e < 4096) KV[(size_t)bh * 4096 + e] = s;
    else Ksum[bh * 64 + (e - 4096)] = s;
  }
}

// ------------- attention apply, in place over Qf ----------------
// out[n, h*64+m] = (sum_d Q[n,d]*KV[m,d]) / (sum_d Q[n,d]*Ksum[d] + eps)
__global__ __launch_bounds__(256) void attn_apply(
    float* __restrict__ Qf, const float* __restrict__ KV,
    const float* __restrict__ Ksum) {
  __shared__ float sKV[64][65];   // [d][m], +1 pad: load phase conflict-free
  __shared__ float sKs[64];
  const int bh = blockIdx.x;
  const int h = bh % Hh, b = bh / Hh;
  const int t = threadIdx.x;

  for (int e = t; e < 4096; e += 256) {
    const int m = e >> 6, d = e & 63;
    sKV[d][m] = KV[(size_t)bh * 4096 + e];
  }
  if (t < 64) sKs[t] = Ksum[bh * 64 + t];
  __syncthreads();

  const int lane = t & 63, rg = t >> 6;
  for (int n0 = 0; n0 < 64; n0 += 4) {
    const int n = blockIdx.y * 64 + n0 + rg;
    const size_t base = ((size_t)(b * Ss + n)) * Dd + h * DKk;
    const float qv = Qf[base + lane];
    float num = 0.f, z = 0.f;
#pragma unroll
    for (int d = 0; d < 64; ++d) {
      const float q = __shfl(qv, d, 64);
      num = fmaf(q, sKV[d][lane], num);
      z = fmaf(q, sKs[d], z);
    }
    Qf[base + lane] = num / (z + 1e-6f);
  }
}

// ---------------------------------------------------------------------------
extern "C" void kernel_launch(void* const* d_in, const int* in_sizes, int n_in,
                              void* d_out, int out_size, void* d_ws, size_t ws_size,
                              hipStream_t stream) {
  const float* q  = (const float*)d_in[0];
  const float* k  = (const float*)d_in[1];
  const float* v  = (const float*)d_in[2];
  const float* Wq = (const float*)d_in[3];
  const float* bq = (const float*)d_in[4];
  const float* Wk = (const float*)d_in[5];
  const float* bk = (const float*)d_in[6];
  const float* Wv = (const float*)d_in[7];
  const float* bv = (const float*)d_in[8];
  const float* Wo = (const float*)d_in[9];
  const float* bo = (const float*)d_in[10];
  float* out = (float*)d_out;

  float* ws   = (float*)d_ws;
  float* Kf   = ws;                                  // 16M floats (64 MB)
  float* Vf   = Kf + (size_t)Mm * Dd;                // 16M floats
  float* KV   = Vf + (size_t)Mm * Dd;                // 64*4096 floats
  float* Ksum = KV + (size_t)Bb * Hh * DKk * DKk;    // 4096 floats
  float* part = Ksum + Bb * Hh * DKk;                // 64*16*4160 floats (~17 MB)
  float* Qf   = Kf;                                  // reuse after KV is reduced

  dim3 gg(Dd / BN, Mm / BM);   // (8, 128)

  gemm_nt_act<1><<<gg, 256, 0, stream>>>(k, Wk, bk, Kf);
  gemm_nt_act<0><<<gg, 256, 0, stream>>>(v, Wv, bv, Vf);
  kv_partial<<<Bb * Hh * NCH, 256, 0, stream>>>(Kf, Vf, part);
  kv_reduce<<<Bb * Hh, 256, 0, stream>>>(part, KV, Ksum);
  gemm_nt_act<1><<<gg, 256, 0, stream>>>(q, Wq, bq, Qf);
  attn_apply<<<dim3(Bb * Hh, Ss / 64), 256, 0, stream>>>(Qf, KV, Ksum);
  gemm_nt_act<0><<<gg, 256, 0, stream>>>(Qf, Wo, bo, out);
}

// Round 3
// 527.560 us; speedup vs baseline: 3.5311x; 3.5311x over previous
//
#include <hip/hip_runtime.h>
#include <math.h>

// Problem constants
#define Bb 4
#define Ss 4096
#define Dd 1024
#define Hh 16
#define DKk 64
#define Mm (Bb * Ss)          // 16384 rows
#define NCH 16                // n-chunks per head for KV partial reduction

typedef __attribute__((ext_vector_type(8))) short bf16x8;
typedef __attribute__((ext_vector_type(4))) float f32x4;

__device__ __forceinline__ unsigned short f2bf(float f) {
  unsigned u = __float_as_uint(f);
  u += 0x7FFFu + ((u >> 16) & 1u);          // round-to-nearest-even
  return (unsigned short)(u >> 16);
}
__device__ __forceinline__ float bf2f(unsigned short s) {
  return __uint_as_float(((unsigned)s) << 16);
}

// ---------------- fp32 -> bf16 conversion (up to 4 tensors per launch) -----
__global__ __launch_bounds__(256) void cvt_f32_bf16(
    const float* __restrict__ s0, const float* __restrict__ s1,
    const float* __restrict__ s2, const float* __restrict__ s3,
    unsigned short* __restrict__ d0, unsigned short* __restrict__ d1,
    unsigned short* __restrict__ d2, unsigned short* __restrict__ d3, int n4) {
  const float* s; unsigned short* d;
  switch (blockIdx.y) {
    case 0:  s = s0; d = d0; break;
    case 1:  s = s1; d = d1; break;
    case 2:  s = s2; d = d2; break;
    default: s = s3; d = d3; break;
  }
  const int i = blockIdx.x * 256 + threadIdx.x;
  if (i < n4) {
    float4 v = ((const float4*)s)[i];
    ushort4 o;
    o.x = f2bf(v.x); o.y = f2bf(v.y); o.z = f2bf(v.z); o.w = f2bf(v.w);
    ((ushort4*)d)[i] = o;
  }
}

// ---------------- bf16 MFMA GEMM: C = act(A[M,K] @ W[N,K]^T + bias) --------
// m97 structure: 128x128 tile, BK=32, 4 waves, 4x4 16x16x32 fragments/wave,
// global_load_lds width-16 staging, 2 barriers per K-step.
template <int ACT, typename OutT>
__global__ __launch_bounds__(256) void gemm_bt_mfma(
    const unsigned short* __restrict__ A,   // [M,1024] bf16 bits
    const unsigned short* __restrict__ W,   // [1024,1024] bf16 bits (N,K)
    const float* __restrict__ bias,
    OutT* __restrict__ C) {
  __shared__ unsigned short Als[128 * 32];
  __shared__ unsigned short Bls[128 * 32];
  const int t = threadIdx.x;
  const int wave = t >> 6, lane = t & 63;
  const int bn = blockIdx.x, bm = blockIdx.y;
  const int wr = (wave >> 1) << 6;   // wave row origin in tile
  const int wc = (wave & 1) << 6;    // wave col origin in tile

  f32x4 acc[4][4];
#pragma unroll
  for (int i = 0; i < 4; ++i)
#pragma unroll
    for (int j = 0; j < 4; ++j) acc[i][j] = (f32x4){0.f, 0.f, 0.f, 0.f};

  // staging: thread t covers LDS bf16 elems [t*8, t*8+8) => row t/4, col (t%4)*8
  const int srow = t >> 2;
  const int scol = (t & 3) << 3;
  const unsigned short* ga0 = A + (size_t)(bm * 128 + srow) * Dd + scol;
  const unsigned short* ga1 = ga0 + (size_t)64 * Dd;
  const unsigned short* gb0 = W + (size_t)(bn * 128 + srow) * Dd + scol;
  const unsigned short* gb1 = gb0 + (size_t)64 * Dd;
  unsigned short* lA = Als + (wave << 9);   // wave-uniform base, HW adds lane*16B
  unsigned short* lB = Bls + (wave << 9);

  const int fr = lane & 15, fq = lane >> 4;
  const unsigned short* rA = Als + (wr + fr) * 32 + fq * 8;
  const unsigned short* rB = Bls + (wc + fr) * 32 + fq * 8;

  for (int k0 = 0; k0 < Dd; k0 += 32) {
    __builtin_amdgcn_global_load_lds(
        (const __attribute__((address_space(1))) void*)(ga0 + k0),
        (__attribute__((address_space(3))) void*)(lA), 16, 0, 0);
    __builtin_amdgcn_global_load_lds(
        (const __attribute__((address_space(1))) void*)(ga1 + k0),
        (__attribute__((address_space(3))) void*)(lA + 2048), 16, 0, 0);  // row 64 = ushort 2048
    __builtin_amdgcn_global_load_lds(
        (const __attribute__((address_space(1))) void*)(gb0 + k0),
        (__attribute__((address_space(3))) void*)(lB), 16, 0, 0);
    __builtin_amdgcn_global_load_lds(
        (const __attribute__((address_space(1))) void*)(gb1 + k0),
        (__attribute__((address_space(3))) void*)(lB + 2048), 16, 0, 0);
    __syncthreads();   // drains vmcnt, staging visible

    bf16x8 af[4], bf[4];
#pragma unroll
    for (int mi = 0; mi < 4; ++mi) af[mi] = *(const bf16x8*)(rA + mi * 16 * 32);
#pragma unroll
    for (int nj = 0; nj < 4; ++nj) bf[nj] = *(const bf16x8*)(rB + nj * 16 * 32);
#pragma unroll
    for (int mi = 0; mi < 4; ++mi)
#pragma unroll
      for (int nj = 0; nj < 4; ++nj)
        acc[mi][nj] = __builtin_amdgcn_mfma_f32_16x16x32_bf16(
            af[mi], bf[nj], acc[mi][nj], 0, 0, 0);
    __syncthreads();   // compute done before next staging overwrite
  }

  // epilogue: C/D layout col=lane&15, row=(lane>>4)*4+reg
  const size_t crow0 = (size_t)bm * 128 + wr + fq * 4;
  const int ccol0 = bn * 128 + wc + fr;
#pragma unroll
  for (int mi = 0; mi < 4; ++mi) {
#pragma unroll
    for (int nj = 0; nj < 4; ++nj) {
      const int col = ccol0 + nj * 16;
      const float bv = bias[col];
#pragma unroll
      for (int r = 0; r < 4; ++r) {
        const size_t row = crow0 + mi * 16 + r;
        float v = acc[mi][nj][r] + bv;
        if (ACT) v = (v > 0.f) ? (v + 1.f) : __expf(v);   // elu(x)+1
        if constexpr (sizeof(OutT) == 2)
          ((unsigned short*)C)[row * Dd + col] = f2bf(v);
        else
          ((float*)C)[row * Dd + col] = v;
      }
    }
  }
}

// ------------- KV partial: per (b,h,chunk) block, 256 rows ----------------
// part[bx][m*64+d] = sum_n V[n,m]*K[n,d];  part[bx][4096+d] = sum_n K[n,d]
__global__ __launch_bounds__(256) void kv_partial(
    const unsigned short* __restrict__ Kf, const unsigned short* __restrict__ Vf,
    float* __restrict__ part) {
  const int bx = blockIdx.x;            // b*H*NCH + h*NCH + chunk
  const int chunk = bx % NCH;
  const int bh = bx / NCH;
  const int h = bh % Hh, b = bh / Hh;
  const int t = threadIdx.x;
  const int tm = t >> 4, td = t & 15;
  __shared__ float sK[8][64];
  __shared__ float sV[8][64];
  float acc[4][4] = {{0.f}};
  float ksr[4] = {0.f, 0.f, 0.f, 0.f};

  const int which = t >> 7;             // 0: K, 1: V
  const int idx = t & 127;
  const int rr = idx >> 4;              // 0..7
  const int dpos = (idx & 15) << 2;     // 0..60
  const int colbase = h * DKk;
  const int rows = Ss / NCH;            // 256

  for (int n0 = 0; n0 < rows; n0 += 8) {
    const int gr = b * Ss + chunk * rows + n0 + rr;
    const unsigned short* src = which ? Vf : Kf;
    ushort4 raw = *(const ushort4*)&src[(size_t)gr * Dd + colbase + dpos];
    __syncthreads();
    float* dst = which ? &sV[rr][dpos] : &sK[rr][dpos];
    dst[0] = bf2f(raw.x); dst[1] = bf2f(raw.y);
    dst[2] = bf2f(raw.z); dst[3] = bf2f(raw.w);
    __syncthreads();
#pragma unroll
    for (int r = 0; r < 8; ++r) {
      float kv[4], vv[4];
#pragma unroll
      for (int j = 0; j < 4; ++j) kv[j] = sK[r][td * 4 + j];
#pragma unroll
      for (int i = 0; i < 4; ++i) vv[i] = sV[r][tm * 4 + i];
#pragma unroll
      for (int i = 0; i < 4; ++i)
#pragma unroll
        for (int j = 0; j < 4; ++j)
          acc[i][j] = fmaf(vv[i], kv[j], acc[i][j]);
      if (tm == 0) {
#pragma unroll
        for (int j = 0; j < 4; ++j) ksr[j] += kv[j];
      }
    }
  }

  float* p = part + (size_t)bx * 4160;
#pragma unroll
  for (int i = 0; i < 4; ++i)
#pragma unroll
    for (int j = 0; j < 4; ++j)
      p[(tm * 4 + i) * 64 + td * 4 + j] = acc[i][j];
  if (tm == 0) {
#pragma unroll
    for (int j = 0; j < 4; ++j) p[4096 + td * 4 + j] = ksr[j];
  }
}

// ------------- KV reduce: sum NCH partials per head ----------------
__global__ __launch_bounds__(256) void kv_reduce(
    const float* __restrict__ part, float* __restrict__ KV,
    float* __restrict__ Ksum) {
  const int bh = blockIdx.x;
  for (int e = threadIdx.x; e < 4160; e += 256) {
    float s = 0.f;
#pragma unroll
    for (int c = 0; c < NCH; ++c)
      s += part[((size_t)bh * NCH + c) * 4160 + e];
    if (e < 4096) KV[(size_t)bh * 4096 + e] = s;
    else Ksum[bh * 64 + (e - 4096)] = s;
  }
}

// ------------- attention apply, in place over Qf (bf16) ----------------
// out[n, h*64+m] = (sum_d Q[n,d]*KV[m,d]) / (sum_d Q[n,d]*Ksum[d] + eps)
__global__ __launch_bounds__(256) void attn_apply(
    unsigned short* __restrict__ Qf, const float* __restrict__ KV,
    const float* __restrict__ Ksum) {
  __shared__ float sKV[64][65];
  __shared__ float sKs[64];
  const int bh = blockIdx.x;
  const int h = bh % Hh, b = bh / Hh;
  const int t = threadIdx.x;

  for (int e = t; e < 4096; e += 256) {
    const int m = e >> 6, d = e & 63;
    sKV[d][m] = KV[(size_t)bh * 4096 + e];
  }
  if (t < 64) sKs[t] = Ksum[bh * 64 + t];
  __syncthreads();

  const int lane = t & 63, rg = t >> 6;
  for (int n0 = 0; n0 < 64; n0 += 4) {
    const int n = blockIdx.y * 64 + n0 + rg;
    const size_t base = ((size_t)(b * Ss + n)) * Dd + h * DKk;
    const float qv = bf2f(Qf[base + lane]);
    float num = 0.f, z = 0.f;
#pragma unroll
    for (int d = 0; d < 64; ++d) {
      const float q = __shfl(qv, d, 64);
      num = fmaf(q, sKV[d][lane], num);
      z = fmaf(q, sKs[d], z);
    }
    Qf[base + lane] = f2bf(num / (z + 1e-6f));
  }
}

// ---------------------------------------------------------------------------
extern "C" void kernel_launch(void* const* d_in, const int* in_sizes, int n_in,
                              void* d_out, int out_size, void* d_ws, size_t ws_size,
                              hipStream_t stream) {
  const float* q  = (const float*)d_in[0];
  const float* k  = (const float*)d_in[1];
  const float* v  = (const float*)d_in[2];
  const float* Wq = (const float*)d_in[3];
  const float* bq = (const float*)d_in[4];
  const float* Wk = (const float*)d_in[5];
  const float* bk = (const float*)d_in[6];
  const float* Wv = (const float*)d_in[7];
  const float* bv = (const float*)d_in[8];
  const float* Wo = (const float*)d_in[9];
  const float* bo = (const float*)d_in[10];
  float* out = (float*)d_out;

  // workspace layout (bf16 stored as ushort)
  unsigned short* cb0 = (unsigned short*)d_ws;          // k_in bf16, later q_in bf16
  unsigned short* cb1 = cb0 + (size_t)Mm * Dd;          // v_in bf16, later 'part' fp32
  unsigned short* Kf  = cb1 + (size_t)Mm * Dd;          // K features, later Q features
  unsigned short* Vf  = Kf  + (size_t)Mm * Dd;          // V features
  unsigned short* Wqb = Vf  + (size_t)Mm * Dd;
  unsigned short* Wkb = Wqb + (size_t)Dd * Dd;
  unsigned short* Wvb = Wkb + (size_t)Dd * Dd;
  unsigned short* Wob = Wvb + (size_t)Dd * Dd;
  float* KV   = (float*)(Wob + (size_t)Dd * Dd);        // 64*4096 floats
  float* Ksum = KV + (size_t)Bb * Hh * DKk * DKk;       // 4096 floats
  float* part = (float*)cb1;                            // 64*16*4160 floats (17MB < 32MB)

  dim3 gg(Dd / 128, Mm / 128);   // (8, 128)

  // weights -> bf16
  cvt_f32_bf16<<<dim3(1024, 4), 256, 0, stream>>>(Wq, Wk, Wv, Wo, Wqb, Wkb, Wvb, Wob,
                                                  (Dd * Dd) / 4);
  // k, v -> bf16
  cvt_f32_bf16<<<dim3(16384, 2), 256, 0, stream>>>(k, v, nullptr, nullptr,
                                                   cb0, cb1, nullptr, nullptr,
                                                   ((size_t)Mm * Dd) / 4);
  gemm_bt_mfma<1, unsigned short><<<gg, 256, 0, stream>>>(cb0, Wkb, bk, Kf);
  gemm_bt_mfma<0, unsigned short><<<gg, 256, 0, stream>>>(cb1, Wvb, bv, Vf);
  kv_partial<<<Bb * Hh * NCH, 256, 0, stream>>>(Kf, Vf, part);
  kv_reduce<<<Bb * Hh, 256, 0, stream>>>(part, KV, Ksum);
  // q -> bf16 (cb0 free after K-projection)
  cvt_f32_bf16<<<dim3(16384, 1), 256, 0, stream>>>(q, nullptr, nullptr, nullptr,
                                                   cb0, nullptr, nullptr, nullptr,
                                                   ((size_t)Mm * Dd) / 4);
  gemm_bt_mfma<1, unsigned short><<<gg, 256, 0, stream>>>(cb0, Wqb, bq, Kf);  // Qf
  attn_apply<<<dim3(Bb * Hh, Ss / 64), 256, 0, stream>>>(Kf, KV, Ksum);
  gemm_bt_mfma<0, float><<<gg, 256, 0, stream>>>(Kf, Wob, bo, out);
}

// Round 4
// 356.579 us; speedup vs baseline: 5.2243x; 1.4795x over previous
//
#include <hip/hip_runtime.h>
#include <math.h>

// Problem constants
#define Bb 4
#define Ss 4096
#define Dd 1024
#define Hh 16
#define DKk 64
#define Mm (Bb * Ss)          // 16384 rows
#define NCH 16                // n-chunks per head for KV partial reduction

typedef __attribute__((ext_vector_type(8))) short bf16x8;
typedef __attribute__((ext_vector_type(4))) float f32x4;

__device__ __forceinline__ unsigned short f2bf(float f) {
  unsigned u = __float_as_uint(f);
  u += 0x7FFFu + ((u >> 16) & 1u);          // round-to-nearest-even
  return (unsigned short)(u >> 16);
}
__device__ __forceinline__ float bf2f(unsigned short s) {
  return __uint_as_float(((unsigned)s) << 16);
}

// ---------------- fp32 -> bf16 conversion (up to 4 tensors per launch) -----
__global__ __launch_bounds__(256) void cvt_f32_bf16(
    const float* __restrict__ s0, const float* __restrict__ s1,
    const float* __restrict__ s2, const float* __restrict__ s3,
    unsigned short* __restrict__ d0, unsigned short* __restrict__ d1,
    unsigned short* __restrict__ d2, unsigned short* __restrict__ d3, int n4) {
  const float* s; unsigned short* d;
  switch (blockIdx.y) {
    case 0:  s = s0; d = d0; break;
    case 1:  s = s1; d = d1; break;
    case 2:  s = s2; d = d2; break;
    default: s = s3; d = d3; break;
  }
  const int i = blockIdx.x * 256 + threadIdx.x;
  if (i < n4) {
    float4 v = ((const float4*)s)[i];
    ushort4 o;
    o.x = f2bf(v.x); o.y = f2bf(v.y); o.z = f2bf(v.z); o.w = f2bf(v.w);
    ((ushort4*)d)[i] = o;
  }
}

// ---------------- bf16 MFMA GEMM: C = act(A[M,K] @ W[N,K]^T + bias) --------
// m97 structure: 128x128 tile, BK=32, 4 waves, 4x4 16x16x32 fragments/wave,
// global_load_lds width-16 staging, 2 barriers per K-step.
template <int ACT, typename OutT>
__global__ __launch_bounds__(256) void gemm_bt_mfma(
    const unsigned short* __restrict__ A,   // [M,1024] bf16 bits
    const unsigned short* __restrict__ W,   // [1024,1024] bf16 bits (N,K)
    const float* __restrict__ bias,
    OutT* __restrict__ C) {
  __shared__ unsigned short Als[128 * 32];
  __shared__ unsigned short Bls[128 * 32];
  const int t = threadIdx.x;
  const int wave = t >> 6, lane = t & 63;
  const int bn = blockIdx.x, bm = blockIdx.y;
  const int wr = (wave >> 1) << 6;   // wave row origin in tile
  const int wc = (wave & 1) << 6;    // wave col origin in tile

  f32x4 acc[4][4];
#pragma unroll
  for (int i = 0; i < 4; ++i)
#pragma unroll
    for (int j = 0; j < 4; ++j) acc[i][j] = (f32x4){0.f, 0.f, 0.f, 0.f};

  // staging: thread t covers LDS bf16 elems [t*8, t*8+8) => row t/4, col (t%4)*8
  const int srow = t >> 2;
  const int scol = (t & 3) << 3;
  const unsigned short* ga0 = A + (size_t)(bm * 128 + srow) * Dd + scol;
  const unsigned short* ga1 = ga0 + (size_t)64 * Dd;
  const unsigned short* gb0 = W + (size_t)(bn * 128 + srow) * Dd + scol;
  const unsigned short* gb1 = gb0 + (size_t)64 * Dd;
  unsigned short* lA = Als + (wave << 9);   // wave-uniform base, HW adds lane*16B
  unsigned short* lB = Bls + (wave << 9);

  const int fr = lane & 15, fq = lane >> 4;
  const unsigned short* rA = Als + (wr + fr) * 32 + fq * 8;
  const unsigned short* rB = Bls + (wc + fr) * 32 + fq * 8;

  for (int k0 = 0; k0 < Dd; k0 += 32) {
    __builtin_amdgcn_global_load_lds(
        (const __attribute__((address_space(1))) void*)(ga0 + k0),
        (__attribute__((address_space(3))) void*)(lA), 16, 0, 0);
    __builtin_amdgcn_global_load_lds(
        (const __attribute__((address_space(1))) void*)(ga1 + k0),
        (__attribute__((address_space(3))) void*)(lA + 2048), 16, 0, 0);  // row 64
    __builtin_amdgcn_global_load_lds(
        (const __attribute__((address_space(1))) void*)(gb0 + k0),
        (__attribute__((address_space(3))) void*)(lB), 16, 0, 0);
    __builtin_amdgcn_global_load_lds(
        (const __attribute__((address_space(1))) void*)(gb1 + k0),
        (__attribute__((address_space(3))) void*)(lB + 2048), 16, 0, 0);
    __syncthreads();   // drains vmcnt, staging visible

    bf16x8 af[4], bf[4];
#pragma unroll
    for (int mi = 0; mi < 4; ++mi) af[mi] = *(const bf16x8*)(rA + mi * 16 * 32);
#pragma unroll
    for (int nj = 0; nj < 4; ++nj) bf[nj] = *(const bf16x8*)(rB + nj * 16 * 32);
#pragma unroll
    for (int mi = 0; mi < 4; ++mi)
#pragma unroll
      for (int nj = 0; nj < 4; ++nj)
        acc[mi][nj] = __builtin_amdgcn_mfma_f32_16x16x32_bf16(
            af[mi], bf[nj], acc[mi][nj], 0, 0, 0);
    __syncthreads();   // compute done before next staging overwrite
  }

  // epilogue: C/D layout col=lane&15, row=(lane>>4)*4+reg
  const size_t crow0 = (size_t)bm * 128 + wr + fq * 4;
  const int ccol0 = bn * 128 + wc + fr;
#pragma unroll
  for (int mi = 0; mi < 4; ++mi) {
#pragma unroll
    for (int nj = 0; nj < 4; ++nj) {
      const int col = ccol0 + nj * 16;
      const float bv = bias[col];
#pragma unroll
      for (int r = 0; r < 4; ++r) {
        const size_t row = crow0 + mi * 16 + r;
        float v = acc[mi][nj][r] + bv;
        if (ACT) v = (v > 0.f) ? (v + 1.f) : __expf(v);   // elu(x)+1
        if constexpr (sizeof(OutT) == 2)
          ((unsigned short*)C)[row * Dd + col] = f2bf(v);
        else
          ((float*)C)[row * Dd + col] = v;
      }
    }
  }
}

// ------------- KV partial: per (b,h,chunk) block, 256 rows ----------------
// part[bx][m*64+d] = sum_n V[n,m]*K[n,d];  part[bx][4096+d] = sum_n K[n,d]
__global__ __launch_bounds__(256) void kv_partial(
    const unsigned short* __restrict__ Kf, const unsigned short* __restrict__ Vf,
    float* __restrict__ part) {
  const int bx = blockIdx.x;            // b*H*NCH + h*NCH + chunk
  const int chunk = bx % NCH;
  const int bh = bx / NCH;
  const int h = bh % Hh, b = bh / Hh;
  const int t = threadIdx.x;
  const int tm = t >> 4, td = t & 15;
  __shared__ float sK[8][64];
  __shared__ float sV[8][64];
  float acc[4][4] = {{0.f}};
  float ksr[4] = {0.f, 0.f, 0.f, 0.f};

  const int which = t >> 7;             // 0: K, 1: V
  const int idx = t & 127;
  const int rr = idx >> 4;              // 0..7
  const int dpos = (idx & 15) << 2;     // 0..60
  const int colbase = h * DKk;
  const int rows = Ss / NCH;            // 256

  for (int n0 = 0; n0 < rows; n0 += 8) {
    const int gr = b * Ss + chunk * rows + n0 + rr;
    const unsigned short* src = which ? Vf : Kf;
    ushort4 raw = *(const ushort4*)&src[(size_t)gr * Dd + colbase + dpos];
    __syncthreads();
    float* dst = which ? &sV[rr][dpos] : &sK[rr][dpos];
    dst[0] = bf2f(raw.x); dst[1] = bf2f(raw.y);
    dst[2] = bf2f(raw.z); dst[3] = bf2f(raw.w);
    __syncthreads();
#pragma unroll
    for (int r = 0; r < 8; ++r) {
      float kv[4], vv[4];
#pragma unroll
      for (int j = 0; j < 4; ++j) kv[j] = sK[r][td * 4 + j];
#pragma unroll
      for (int i = 0; i < 4; ++i) vv[i] = sV[r][tm * 4 + i];
#pragma unroll
      for (int i = 0; i < 4; ++i)
#pragma unroll
        for (int j = 0; j < 4; ++j)
          acc[i][j] = fmaf(vv[i], kv[j], acc[i][j]);
      if (tm == 0) {
#pragma unroll
        for (int j = 0; j < 4; ++j) ksr[j] += kv[j];
      }
    }
  }

  float* p = part + (size_t)bx * 4160;
#pragma unroll
  for (int i = 0; i < 4; ++i)
#pragma unroll
    for (int j = 0; j < 4; ++j)
      p[(tm * 4 + i) * 64 + td * 4 + j] = acc[i][j];
  if (tm == 0) {
#pragma unroll
    for (int j = 0; j < 4; ++j) p[4096 + td * 4 + j] = ksr[j];
  }
}

// ------------- KV reduce: sum NCH partials per head ----------------
__global__ __launch_bounds__(256) void kv_reduce(
    const float* __restrict__ part, float* __restrict__ KV,
    float* __restrict__ Ksum) {
  const int bh = blockIdx.x;
  for (int e = threadIdx.x; e < 4160; e += 256) {
    float s = 0.f;
#pragma unroll
    for (int c = 0; c < NCH; ++c)
      s += part[((size_t)bh * NCH + c) * 4160 + e];
    if (e < 4096) KV[(size_t)bh * 4096 + e] = s;
    else Ksum[bh * 64 + (e - 4096)] = s;
  }
}

// ------------- attention apply via MFMA, in place over Qf (bf16) ----------
// out[n, h*64+m] = (sum_d Q[n,d]*KV[m,d]) / (sum_d Q[n,d]*Ksum[d] + eps)
// Per block: one (b,h), 256 rows. 4 waves x 64 rows. K=64 = 2 mfma k-steps.
// z computed via an extra MFMA whose B col 0 = Ksum (same C layout as num).
__global__ __launch_bounds__(256) void attn_mfma(
    unsigned short* __restrict__ Qf, const float* __restrict__ KV,
    const float* __restrict__ Ksum) {
  const int bh = blockIdx.x;
  const int h = bh & (Hh - 1), b = bh >> 4;
  const int t = threadIdx.x;
  const int wave = t >> 6, lane = t & 63;
  const int fr = lane & 15, fq = lane >> 4;

  // B fragments: col = nj*16+fr (KV row m), k = fq*8 + ks*32 (KV col d)
  bf16x8 bfrag[4][2];
  const float* kvb = KV + (size_t)bh * 4096;
#pragma unroll
  for (int nj = 0; nj < 4; ++nj)
#pragma unroll
    for (int ks = 0; ks < 2; ++ks) {
      const float* src = kvb + (nj * 16 + fr) * 64 + ks * 32 + fq * 8;
      const float4 lo = *(const float4*)src;
      const float4 hi = *(const float4*)(src + 4);
      bf16x8 f;
      f[0] = (short)f2bf(lo.x); f[1] = (short)f2bf(lo.y);
      f[2] = (short)f2bf(lo.z); f[3] = (short)f2bf(lo.w);
      f[4] = (short)f2bf(hi.x); f[5] = (short)f2bf(hi.y);
      f[6] = (short)f2bf(hi.z); f[7] = (short)f2bf(hi.w);
      bfrag[nj][ks] = f;
    }
  // z fragment: col 0 holds Ksum, cols 1..15 zero
  bf16x8 zfrag[2];
#pragma unroll
  for (int ks = 0; ks < 2; ++ks) {
    bf16x8 f = (bf16x8){0, 0, 0, 0, 0, 0, 0, 0};
    if (fr == 0) {
      const float* src = Ksum + bh * 64 + ks * 32 + fq * 8;
      const float4 lo = *(const float4*)src;
      const float4 hi = *(const float4*)(src + 4);
      f[0] = (short)f2bf(lo.x); f[1] = (short)f2bf(lo.y);
      f[2] = (short)f2bf(lo.z); f[3] = (short)f2bf(lo.w);
      f[4] = (short)f2bf(hi.x); f[5] = (short)f2bf(hi.y);
      f[6] = (short)f2bf(hi.z); f[7] = (short)f2bf(hi.w);
    }
    zfrag[ks] = f;
  }

  // A fragments: row = fr (global row0 + mi*16 + fr), k = fq*8 + ks*32
  const size_t row0 = (size_t)b * Ss + (size_t)blockIdx.y * 256 + wave * 64;
  unsigned short* qbase = Qf + row0 * Dd + h * DKk;
  bf16x8 afrag[4][2];
#pragma unroll
  for (int mi = 0; mi < 4; ++mi)
#pragma unroll
    for (int ks = 0; ks < 2; ++ks)
      afrag[mi][ks] =
          *(const bf16x8*)(qbase + (size_t)(mi * 16 + fr) * Dd + ks * 32 + fq * 8);

  f32x4 acc[4][4], zacc[4];
#pragma unroll
  for (int mi = 0; mi < 4; ++mi) {
    zacc[mi] = (f32x4){0.f, 0.f, 0.f, 0.f};
#pragma unroll
    for (int nj = 0; nj < 4; ++nj) acc[mi][nj] = (f32x4){0.f, 0.f, 0.f, 0.f};
  }
#pragma unroll
  for (int mi = 0; mi < 4; ++mi)
#pragma unroll
    for (int ks = 0; ks < 2; ++ks) {
      zacc[mi] = __builtin_amdgcn_mfma_f32_16x16x32_bf16(
          afrag[mi][ks], zfrag[ks], zacc[mi], 0, 0, 0);
#pragma unroll
      for (int nj = 0; nj < 4; ++nj)
        acc[mi][nj] = __builtin_amdgcn_mfma_f32_16x16x32_bf16(
            afrag[mi][ks], bfrag[nj][ks], acc[mi][nj], 0, 0, 0);
    }

  // epilogue: C layout col=fr, row=fq*4+r. z[row] sits in lane (fq,0).
#pragma unroll
  for (int mi = 0; mi < 4; ++mi)
#pragma unroll
    for (int r = 0; r < 4; ++r) {
      const float zv = __shfl(zacc[mi][r], lane & 48) + 1e-6f;
      const float rz = 1.0f / zv;
      const size_t ro = (size_t)(mi * 16 + fq * 4 + r) * Dd;
#pragma unroll
      for (int nj = 0; nj < 4; ++nj)
        qbase[ro + nj * 16 + fr] = f2bf(acc[mi][nj][r] * rz);
    }
}

// ---------------------------------------------------------------------------
extern "C" void kernel_launch(void* const* d_in, const int* in_sizes, int n_in,
                              void* d_out, int out_size, void* d_ws, size_t ws_size,
                              hipStream_t stream) {
  const float* q  = (const float*)d_in[0];
  const float* k  = (const float*)d_in[1];
  const float* v  = (const float*)d_in[2];
  const float* Wq = (const float*)d_in[3];
  const float* bq = (const float*)d_in[4];
  const float* Wk = (const float*)d_in[5];
  const float* bk = (const float*)d_in[6];
  const float* Wv = (const float*)d_in[7];
  const float* bv = (const float*)d_in[8];
  const float* Wo = (const float*)d_in[9];
  const float* bo = (const float*)d_in[10];
  float* out = (float*)d_out;

  // workspace layout (bf16 stored as ushort)
  unsigned short* cb0 = (unsigned short*)d_ws;          // k_in bf16, later q_in bf16
  unsigned short* cb1 = cb0 + (size_t)Mm * Dd;          // v_in bf16, later 'part' fp32
  unsigned short* Kf  = cb1 + (size_t)Mm * Dd;          // K features, later Q features
  unsigned short* Vf  = Kf  + (size_t)Mm * Dd;          // V features
  unsigned short* Wqb = Vf  + (size_t)Mm * Dd;
  unsigned short* Wkb = Wqb + (size_t)Dd * Dd;
  unsigned short* Wvb = Wkb + (size_t)Dd * Dd;
  unsigned short* Wob = Wvb + (size_t)Dd * Dd;
  float* KV   = (float*)(Wob + (size_t)Dd * Dd);        // 64*4096 floats
  float* Ksum = KV + (size_t)Bb * Hh * DKk * DKk;       // 4096 floats
  float* part = (float*)cb1;                            // 64*16*4160 floats (17MB < 32MB)

  dim3 gg(Dd / 128, Mm / 128);   // (8, 128)

  // weights -> bf16
  cvt_f32_bf16<<<dim3(1024, 4), 256, 0, stream>>>(Wq, Wk, Wv, Wo, Wqb, Wkb, Wvb, Wob,
                                                  (Dd * Dd) / 4);
  // k, v -> bf16
  cvt_f32_bf16<<<dim3(16384, 2), 256, 0, stream>>>(k, v, nullptr, nullptr,
                                                   cb0, cb1, nullptr, nullptr,
                                                   ((size_t)Mm * Dd) / 4);
  gemm_bt_mfma<1, unsigned short><<<gg, 256, 0, stream>>>(cb0, Wkb, bk, Kf);
  gemm_bt_mfma<0, unsigned short><<<gg, 256, 0, stream>>>(cb1, Wvb, bv, Vf);
  kv_partial<<<Bb * Hh * NCH, 256, 0, stream>>>(Kf, Vf, part);
  kv_reduce<<<Bb * Hh, 256, 0, stream>>>(part, KV, Ksum);
  // q -> bf16 (cb0 free after K-projection)
  cvt_f32_bf16<<<dim3(16384, 1), 256, 0, stream>>>(q, nullptr, nullptr, nullptr,
                                                   cb0, nullptr, nullptr, nullptr,
                                                   ((size_t)Mm * Dd) / 4);
  gemm_bt_mfma<1, unsigned short><<<gg, 256, 0, stream>>>(cb0, Wqb, bq, Kf);  // Qf
  attn_mfma<<<dim3(Bb * Hh, Ss / 256), 256, 0, stream>>>(Kf, KV, Ksum);
  gemm_bt_mfma<0, float><<<gg, 256, 0, stream>>>(Kf, Wob, bo, out);
}

// Round 5
// 295.634 us; speedup vs baseline: 6.3013x; 1.2062x over previous
//
#include <hip/hip_runtime.h>
#include <math.h>

// Problem constants
#define Bb 4
#define Ss 4096
#define Dd 1024
#define Hh 16
#define DKk 64
#define Mm (Bb * Ss)          // 16384 rows
#define NCH 16                // n-chunks per head for KV partial reduction

typedef __attribute__((ext_vector_type(8))) short bf16x8;
typedef __attribute__((ext_vector_type(4))) float f32x4;

__device__ __forceinline__ unsigned short f2bf(float f) {
  unsigned u = __float_as_uint(f);
  u += 0x7FFFu + ((u >> 16) & 1u);          // round-to-nearest-even
  return (unsigned short)(u >> 16);
}
__device__ __forceinline__ float bf2f(unsigned short s) {
  return __uint_as_float(((unsigned)s) << 16);
}

#define GLOAD(dst, src)                                                     \
  __builtin_amdgcn_global_load_lds(                                         \
      (const __attribute__((address_space(1))) void*)(src),                 \
      (__attribute__((address_space(3))) void*)(dst), 16, 0, 0)

// ---------------- fp32 -> bf16 conversion (up to 4 tensors per launch) -----
__global__ __launch_bounds__(256) void cvt_f32_bf16(
    const float* __restrict__ s0, const float* __restrict__ s1,
    const float* __restrict__ s2, const float* __restrict__ s3,
    unsigned short* __restrict__ d0, unsigned short* __restrict__ d1,
    unsigned short* __restrict__ d2, unsigned short* __restrict__ d3, int n4) {
  const float* s; unsigned short* d;
  switch (blockIdx.y) {
    case 0:  s = s0; d = d0; break;
    case 1:  s = s1; d = d1; break;
    case 2:  s = s2; d = d2; break;
    default: s = s3; d = d3; break;
  }
  const int i = blockIdx.x * 256 + threadIdx.x;
  if (i < n4) {
    float4 v = ((const float4*)s)[i];
    ushort4 o;
    o.x = f2bf(v.x); o.y = f2bf(v.y); o.z = f2bf(v.z); o.w = f2bf(v.w);
    ((ushort4*)d)[i] = o;
  }
}

// ---------------- 256x256 deep-pipelined bf16 MFMA GEMM --------------------
// C = act(A[M,1024] @ W[1024,1024]^T + bias). BK=64, 512 thr / 8 waves (2x4).
// 4 phases per K-tile: {12 ds_read_b128 -> 16 MFMA (setprio)} + barrier.
// Staging of tile t+1 at P0 (A) / P1 (B) via global_load_lds; counted
// s_waitcnt vmcnt(4) at P0 only (never 0 in-loop). T2 XOR swizzle on LDS
// (inverse pre-applied to the GLOBAL source; linear LDS dest, G21).
#define PHASE(mh, nh)                                                        \
  {                                                                          \
    bf16x8 af[4][2], bv_[2][2];                                              \
    _Pragma("unroll") for (int mi = 0; mi < 4; ++mi)                         \
      _Pragma("unroll") for (int ks = 0; ks < 2; ++ks)                       \
        af[mi][ks] = *(const bf16x8*)(bufA +                                 \
            (rowA0 + (mh) * 64 + mi * 16) * 64 + (swz_rd ^ (ks * 32)));      \
    _Pragma("unroll") for (int ni = 0; ni < 2; ++ni)                         \
      _Pragma("unroll") for (int ks = 0; ks < 2; ++ks)                       \
        bv_[ni][ks] = *(const bf16x8*)(bufB +                                \
            (rowB0 + (nh) * 32 + ni * 16) * 64 + (swz_rd ^ (ks * 32)));      \
    __builtin_amdgcn_s_setprio(1);                                           \
    _Pragma("unroll") for (int mi = 0; mi < 4; ++mi)                         \
      _Pragma("unroll") for (int ni = 0; ni < 2; ++ni)                       \
        _Pragma("unroll") for (int ks = 0; ks < 2; ++ks)                     \
          acc[(mh) * 4 + mi][(nh) * 2 + ni] =                                \
              __builtin_amdgcn_mfma_f32_16x16x32_bf16(                       \
                  af[mi][ks], bv_[ni][ks],                                   \
                  acc[(mh) * 4 + mi][(nh) * 2 + ni], 0, 0, 0);               \
    __builtin_amdgcn_s_setprio(0);                                           \
  }

template <int ACT, typename OutT>
__global__ __launch_bounds__(512, 2) void gemm256(
    const unsigned short* __restrict__ A,   // [M,1024] bf16 bits
    const unsigned short* __restrict__ W,   // [1024,1024] bf16 bits (N,K)
    const float* __restrict__ bias,
    OutT* __restrict__ C) {
  __shared__ __align__(16) unsigned short lds[2 * 32768];  // 128 KiB
  const int t = threadIdx.x;
  const int wave = t >> 6, lane = t & 63;
  const int wm = wave >> 2, wn = wave & 3;
  const int fr = lane & 15, fq = lane >> 4;

  // XCD-bijective block swizzle (256 wgs, 256 % 8 == 0)
  int wg = blockIdx.x + gridDim.x * blockIdx.y;
  wg = ((wg & 7) << 5) | (wg >> 3);
  const int bm = wg >> 2, bn = wg & 3;

  f32x4 acc[8][4];
#pragma unroll
  for (int i = 0; i < 8; ++i)
#pragma unroll
    for (int j = 0; j < 4; ++j) acc[i][j] = (f32x4){0.f, 0.f, 0.f, 0.f};

  // staging geometry: load l covers LDS linear slot (l*512+t)*16B
  const int rbase = t >> 3;                              // row for l=0
  const int swz_st = ((t & 7) ^ ((t >> 3) & 7)) << 3;    // inverse swizzle (elems)
  const unsigned short* gA[4];
  const unsigned short* gB[4];
#pragma unroll
  for (int l = 0; l < 4; ++l) {
    const int r = l * 64 + rbase;
    gA[l] = A + (size_t)(bm * 256 + r) * Dd + swz_st;
    gB[l] = W + (size_t)(bn * 256 + r) * Dd + swz_st;
  }
  const int dstoff = wave * 512;                         // elems; HW adds lane*16B

  // ds_read geometry (swizzled)
  const int rowA0 = wm * 128 + fr;
  const int rowB0 = wn * 64 + fr;
  const int swz_rd = (fq * 8) ^ ((fr & 7) << 3);

  // prologue: stage tile 0 -> buf0 (8 loads/thread)
#pragma unroll
  for (int l = 0; l < 4; ++l) {
    GLOAD(lds + l * 4096 + dstoff, gA[l]);
    GLOAD(lds + 16384 + l * 4096 + dstoff, gB[l]);
  }

  for (int tt = 0; tt < 16; ++tt) {
    unsigned short* bufA = lds + (tt & 1) * 32768;
    unsigned short* bufB = bufA + 16384;
    unsigned short* nA = lds + ((tt & 1) ^ 1) * 32768;
    unsigned short* nB = nA + 16384;
    const int kpre = (tt < 15 ? tt + 1 : 15) * 64;  // clamp: harmless re-stage

    // P0: issue next-A, drain current tile (counted), compute quadrant (0,0)
#pragma unroll
    for (int l = 0; l < 4; ++l) GLOAD(nA + l * 4096 + dstoff, gA[l] + kpre);
    asm volatile("s_waitcnt vmcnt(4)" ::: "memory");
    __builtin_amdgcn_s_barrier();
    PHASE(0, 0)
    __builtin_amdgcn_s_barrier();
    // P1: issue next-B, compute quadrant (0,1)
#pragma unroll
    for (int l = 0; l < 4; ++l) GLOAD(nB + l * 4096 + dstoff, gB[l] + kpre);
    PHASE(0, 1)
    __builtin_amdgcn_s_barrier();
    // P2
    PHASE(1, 0)
    __builtin_amdgcn_s_barrier();
    // P3
    PHASE(1, 1)
    __builtin_amdgcn_s_barrier();
  }

  // epilogue: C/D layout col=lane&15, row=(lane>>4)*4+reg
  const size_t row0 = (size_t)bm * 256 + wm * 128 + fq * 4;
  const int col0 = bn * 256 + wn * 64 + fr;
#pragma unroll
  for (int mi = 0; mi < 8; ++mi) {
#pragma unroll
    for (int ni = 0; ni < 4; ++ni) {
      const int col = col0 + ni * 16;
      const float bvl = bias[col];
#pragma unroll
      for (int r = 0; r < 4; ++r) {
        const size_t row = row0 + mi * 16 + r;
        float vv = acc[mi][ni][r] + bvl;
        if (ACT) vv = (vv > 0.f) ? (vv + 1.f) : __expf(vv);   // elu(x)+1
        if constexpr (sizeof(OutT) == 2)
          ((unsigned short*)C)[row * Dd + col] = f2bf(vv);
        else
          ((float*)C)[row * Dd + col] = vv;
      }
    }
  }
}

// ------------- KV partial: per (b,h,chunk) block, 256 rows ----------------
// part[bx][m*64+d] = sum_n V[n,m]*K[n,d];  part[bx][4096+d] = sum_n K[n,d]
__global__ __launch_bounds__(256) void kv_partial(
    const unsigned short* __restrict__ Kf, const unsigned short* __restrict__ Vf,
    float* __restrict__ part) {
  const int bx = blockIdx.x;            // b*H*NCH + h*NCH + chunk
  const int chunk = bx % NCH;
  const int bh = bx / NCH;
  const int h = bh % Hh, b = bh / Hh;
  const int t = threadIdx.x;
  const int tm = t >> 4, td = t & 15;
  __shared__ float sK[8][64];
  __shared__ float sV[8][64];
  float acc[4][4] = {{0.f}};
  float ksr[4] = {0.f, 0.f, 0.f, 0.f};

  const int which = t >> 7;             // 0: K, 1: V
  const int idx = t & 127;
  const int rr = idx >> 4;              // 0..7
  const int dpos = (idx & 15) << 2;     // 0..60
  const int colbase = h * DKk;
  const int rows = Ss / NCH;            // 256

  for (int n0 = 0; n0 < rows; n0 += 8) {
    const int gr = b * Ss + chunk * rows + n0 + rr;
    const unsigned short* src = which ? Vf : Kf;
    ushort4 raw = *(const ushort4*)&src[(size_t)gr * Dd + colbase + dpos];
    __syncthreads();
    float* dst = which ? &sV[rr][dpos] : &sK[rr][dpos];
    dst[0] = bf2f(raw.x); dst[1] = bf2f(raw.y);
    dst[2] = bf2f(raw.z); dst[3] = bf2f(raw.w);
    __syncthreads();
#pragma unroll
    for (int r = 0; r < 8; ++r) {
      float kv[4], vv[4];
#pragma unroll
      for (int j = 0; j < 4; ++j) kv[j] = sK[r][td * 4 + j];
#pragma unroll
      for (int i = 0; i < 4; ++i) vv[i] = sV[r][tm * 4 + i];
#pragma unroll
      for (int i = 0; i < 4; ++i)
#pragma unroll
        for (int j = 0; j < 4; ++j)
          acc[i][j] = fmaf(vv[i], kv[j], acc[i][j]);
      if (tm == 0) {
#pragma unroll
        for (int j = 0; j < 4; ++j) ksr[j] += kv[j];
      }
    }
  }

  float* p = part + (size_t)bx * 4160;
#pragma unroll
  for (int i = 0; i < 4; ++i)
#pragma unroll
    for (int j = 0; j < 4; ++j)
      p[(tm * 4 + i) * 64 + td * 4 + j] = acc[i][j];
  if (tm == 0) {
#pragma unroll
    for (int j = 0; j < 4; ++j) p[4096 + td * 4 + j] = ksr[j];
  }
}

// ------------- KV reduce: sum NCH partials per head ----------------
__global__ __launch_bounds__(256) void kv_reduce(
    const float* __restrict__ part, float* __restrict__ KV,
    float* __restrict__ Ksum) {
  const int bh = blockIdx.x;
  for (int e = threadIdx.x; e < 4160; e += 256) {
    float s = 0.f;
#pragma unroll
    for (int c = 0; c < NCH; ++c)
      s += part[((size_t)bh * NCH + c) * 4160 + e];
    if (e < 4096) KV[(size_t)bh * 4096 + e] = s;
    else Ksum[bh * 64 + (e - 4096)] = s;
  }
}

// ------------- attention apply via MFMA, in place over Qf (bf16) ----------
__global__ __launch_bounds__(256) void attn_mfma(
    unsigned short* __restrict__ Qf, const float* __restrict__ KV,
    const float* __restrict__ Ksum) {
  const int bh = blockIdx.x;
  const int h = bh & (Hh - 1), b = bh >> 4;
  const int t = threadIdx.x;
  const int wave = t >> 6, lane = t & 63;
  const int fr = lane & 15, fq = lane >> 4;

  bf16x8 bfrag[4][2];
  const float* kvb = KV + (size_t)bh * 4096;
#pragma unroll
  for (int nj = 0; nj < 4; ++nj)
#pragma unroll
    for (int ks = 0; ks < 2; ++ks) {
      const float* src = kvb + (nj * 16 + fr) * 64 + ks * 32 + fq * 8;
      const float4 lo = *(const float4*)src;
      const float4 hi = *(const float4*)(src + 4);
      bf16x8 f;
      f[0] = (short)f2bf(lo.x); f[1] = (short)f2bf(lo.y);
      f[2] = (short)f2bf(lo.z); f[3] = (short)f2bf(lo.w);
      f[4] = (short)f2bf(hi.x); f[5] = (short)f2bf(hi.y);
      f[6] = (short)f2bf(hi.z); f[7] = (short)f2bf(hi.w);
      bfrag[nj][ks] = f;
    }
  bf16x8 zfrag[2];
#pragma unroll
  for (int ks = 0; ks < 2; ++ks) {
    bf16x8 f = (bf16x8){0, 0, 0, 0, 0, 0, 0, 0};
    if (fr == 0) {
      const float* src = Ksum + bh * 64 + ks * 32 + fq * 8;
      const float4 lo = *(const float4*)src;
      const float4 hi = *(const float4*)(src + 4);
      f[0] = (short)f2bf(lo.x); f[1] = (short)f2bf(lo.y);
      f[2] = (short)f2bf(lo.z); f[3] = (short)f2bf(lo.w);
      f[4] = (short)f2bf(hi.x); f[5] = (short)f2bf(hi.y);
      f[6] = (short)f2bf(hi.z); f[7] = (short)f2bf(hi.w);
    }
    zfrag[ks] = f;
  }

  const size_t row0 = (size_t)b * Ss + (size_t)blockIdx.y * 256 + wave * 64;
  unsigned short* qbase = Qf + row0 * Dd + h * DKk;
  bf16x8 afrag[4][2];
#pragma unroll
  for (int mi = 0; mi < 4; ++mi)
#pragma unroll
    for (int ks = 0; ks < 2; ++ks)
      afrag[mi][ks] =
          *(const bf16x8*)(qbase + (size_t)(mi * 16 + fr) * Dd + ks * 32 + fq * 8);

  f32x4 acc[4][4], zacc[4];
#pragma unroll
  for (int mi = 0; mi < 4; ++mi) {
    zacc[mi] = (f32x4){0.f, 0.f, 0.f, 0.f};
#pragma unroll
    for (int nj = 0; nj < 4; ++nj) acc[mi][nj] = (f32x4){0.f, 0.f, 0.f, 0.f};
  }
#pragma unroll
  for (int mi = 0; mi < 4; ++mi)
#pragma unroll
    for (int ks = 0; ks < 2; ++ks) {
      zacc[mi] = __builtin_amdgcn_mfma_f32_16x16x32_bf16(
          afrag[mi][ks], zfrag[ks], zacc[mi], 0, 0, 0);
#pragma unroll
      for (int nj = 0; nj < 4; ++nj)
        acc[mi][nj] = __builtin_amdgcn_mfma_f32_16x16x32_bf16(
            afrag[mi][ks], bfrag[nj][ks], acc[mi][nj], 0, 0, 0);
    }

#pragma unroll
  for (int mi = 0; mi < 4; ++mi)
#pragma unroll
    for (int r = 0; r < 4; ++r) {
      const float zv = __shfl(zacc[mi][r], lane & 48) + 1e-6f;
      const float rz = 1.0f / zv;
      const size_t ro = (size_t)(mi * 16 + fq * 4 + r) * Dd;
#pragma unroll
      for (int nj = 0; nj < 4; ++nj)
        qbase[ro + nj * 16 + fr] = f2bf(acc[mi][nj][r] * rz);
    }
}

// ---------------------------------------------------------------------------
extern "C" void kernel_launch(void* const* d_in, const int* in_sizes, int n_in,
                              void* d_out, int out_size, void* d_ws, size_t ws_size,
                              hipStream_t stream) {
  const float* q  = (const float*)d_in[0];
  const float* k  = (const float*)d_in[1];
  const float* v  = (const float*)d_in[2];
  const float* Wq = (const float*)d_in[3];
  const float* bq = (const float*)d_in[4];
  const float* Wk = (const float*)d_in[5];
  const float* bk = (const float*)d_in[6];
  const float* Wv = (const float*)d_in[7];
  const float* bv = (const float*)d_in[8];
  const float* Wo = (const float*)d_in[9];
  const float* bo = (const float*)d_in[10];
  float* out = (float*)d_out;

  // workspace layout (bf16 stored as ushort)
  unsigned short* cb0 = (unsigned short*)d_ws;          // k_in bf16, later q_in bf16
  unsigned short* cb1 = cb0 + (size_t)Mm * Dd;          // v_in bf16, later 'part' fp32
  unsigned short* Kf  = cb1 + (size_t)Mm * Dd;          // K features, later Q features
  unsigned short* Vf  = Kf  + (size_t)Mm * Dd;          // V features
  unsigned short* Wqb = Vf  + (size_t)Mm * Dd;
  unsigned short* Wkb = Wqb + (size_t)Dd * Dd;
  unsigned short* Wvb = Wkb + (size_t)Dd * Dd;
  unsigned short* Wob = Wvb + (size_t)Dd * Dd;
  float* KV   = (float*)(Wob + (size_t)Dd * Dd);        // 64*4096 floats
  float* Ksum = KV + (size_t)Bb * Hh * DKk * DKk;       // 4096 floats
  float* part = (float*)cb1;                            // 64*16*4160 floats

  dim3 gg(Dd / 256, Mm / 256);   // (4, 64) = 256 wgs

  // weights -> bf16
  cvt_f32_bf16<<<dim3(1024, 4), 256, 0, stream>>>(Wq, Wk, Wv, Wo, Wqb, Wkb, Wvb, Wob,
                                                  (Dd * Dd) / 4);
  // k, v -> bf16
  cvt_f32_bf16<<<dim3(16384, 2), 256, 0, stream>>>(k, v, nullptr, nullptr,
                                                   cb0, cb1, nullptr, nullptr,
                                                   ((size_t)Mm * Dd) / 4);
  gemm256<1, unsigned short><<<gg, 512, 0, stream>>>(cb0, Wkb, bk, Kf);
  gemm256<0, unsigned short><<<gg, 512, 0, stream>>>(cb1, Wvb, bv, Vf);
  kv_partial<<<Bb * Hh * NCH, 256, 0, stream>>>(Kf, Vf, part);
  kv_reduce<<<Bb * Hh, 256, 0, stream>>>(part, KV, Ksum);
  // q -> bf16 (cb0 free after K-projection)
  cvt_f32_bf16<<<dim3(16384, 1), 256, 0, stream>>>(q, nullptr, nullptr, nullptr,
                                                   cb0, nullptr, nullptr, nullptr,
                                                   ((size_t)Mm * Dd) / 4);
  gemm256<1, unsigned short><<<gg, 512, 0, stream>>>(cb0, Wqb, bq, Kf);  // Qf
  attn_mfma<<<dim3(Bb * Hh, Ss / 256), 256, 0, stream>>>(Kf, KV, Ksum);
  gemm256<0, float><<<gg, 512, 0, stream>>>(Kf, Wob, bo, out);
}

// Round 6
// 295.207 us; speedup vs baseline: 6.3104x; 1.0014x over previous
//
#include <hip/hip_runtime.h>
#include <math.h>

// Problem constants
#define Bb 4
#define Ss 4096
#define Dd 1024
#define Hh 16
#define DKk 64
#define Mm (Bb * Ss)          // 16384 rows
#define NCH 16                // n-chunks per head for KV partial reduction

typedef __attribute__((ext_vector_type(8))) short bf16x8;
typedef __attribute__((ext_vector_type(4))) float f32x4;

__device__ __forceinline__ unsigned short f2bf(float f) {
  unsigned u = __float_as_uint(f);
  u += 0x7FFFu + ((u >> 16) & 1u);          // round-to-nearest-even
  return (unsigned short)(u >> 16);
}
__device__ __forceinline__ float bf2f(unsigned short s) {
  return __uint_as_float(((unsigned)s) << 16);
}
__device__ __forceinline__ unsigned cvt2(float lo, float hi) {
  unsigned r;
  asm("v_cvt_pk_bf16_f32 %0, %1, %2" : "=v"(r) : "v"(lo), "v"(hi));
  return r;   // low 16 = bf16(lo), high 16 = bf16(hi), RNE
}

#define GLOAD(dst, src)                                                     \
  __builtin_amdgcn_global_load_lds(                                         \
      (const __attribute__((address_space(1))) void*)(src),                 \
      (__attribute__((address_space(3))) void*)(dst), 16, 0, 0)

// ---------------- fp32 -> bf16 conversion (up to 4 tensors per launch) -----
__global__ __launch_bounds__(256) void cvt_f32_bf16(
    const float* __restrict__ s0, const float* __restrict__ s1,
    const float* __restrict__ s2, const float* __restrict__ s3,
    unsigned short* __restrict__ d0, unsigned short* __restrict__ d1,
    unsigned short* __restrict__ d2, unsigned short* __restrict__ d3, int n4) {
  const float* s; unsigned short* d;
  switch (blockIdx.y) {
    case 0:  s = s0; d = d0; break;
    case 1:  s = s1; d = d1; break;
    case 2:  s = s2; d = d2; break;
    default: s = s3; d = d3; break;
  }
  const int i = blockIdx.x * 256 + threadIdx.x;
  if (i < n4) {
    float4 v = ((const float4*)s)[i];
    ushort4 o;
    o.x = f2bf(v.x); o.y = f2bf(v.y); o.z = f2bf(v.z); o.w = f2bf(v.w);
    ((ushort4*)d)[i] = o;
  }
}

// ---------------- 256x256 deep-pipelined bf16 MFMA GEMM --------------------
// C = act(A[M,1024] @ W[1024,1024]^T + bias). BK=64, 512 thr / 8 waves (2x4).
// AT=float: fused fp32->bf16 A-staging (reg-stage + cvt_pk + swizzled
// ds_write); AT=ushort: gload_lds A path. B always gload_lds (pre-swizzled
// global source, linear LDS dest, G21). Counted vmcnt, never 0 in-loop.
#define PHASE(mh, nh)                                                        \
  {                                                                          \
    bf16x8 af[4][2], bv_[2][2];                                              \
    _Pragma("unroll") for (int mi = 0; mi < 4; ++mi)                         \
      _Pragma("unroll") for (int ks = 0; ks < 2; ++ks)                       \
        af[mi][ks] = *(const bf16x8*)(bufA +                                 \
            (rowA0 + (mh) * 64 + mi * 16) * 64 + (swz_rd ^ (ks * 32)));      \
    _Pragma("unroll") for (int ni = 0; ni < 2; ++ni)                         \
      _Pragma("unroll") for (int ks = 0; ks < 2; ++ks)                       \
        bv_[ni][ks] = *(const bf16x8*)(bufB +                                \
            (rowB0 + (nh) * 32 + ni * 16) * 64 + (swz_rd ^ (ks * 32)));      \
    __builtin_amdgcn_s_setprio(1);                                           \
    _Pragma("unroll") for (int mi = 0; mi < 4; ++mi)                         \
      _Pragma("unroll") for (int ni = 0; ni < 2; ++ni)                       \
        _Pragma("unroll") for (int ks = 0; ks < 2; ++ks)                     \
          acc[(mh) * 4 + mi][(nh) * 2 + ni] =                                \
              __builtin_amdgcn_mfma_f32_16x16x32_bf16(                       \
                  af[mi][ks], bv_[ni][ks],                                   \
                  acc[(mh) * 4 + mi][(nh) * 2 + ni], 0, 0, 0);               \
    __builtin_amdgcn_s_setprio(0);                                           \
  }

template <int ACT, typename AT, typename OutT>
__global__ __launch_bounds__(512, 2) void gemm256(
    const AT* __restrict__ A,               // [M,1024] fp32 or bf16 bits
    const unsigned short* __restrict__ W,   // [1024,1024] bf16 bits (N,K)
    const float* __restrict__ bias,
    OutT* __restrict__ C) {
  constexpr bool AF32 = (sizeof(AT) == 4);
  __shared__ __align__(16) unsigned short lds[2 * 32768];  // 128 KiB
  const int t = threadIdx.x;
  const int wave = t >> 6, lane = t & 63;
  const int wm = wave >> 2, wn = wave & 3;
  const int fr = lane & 15, fq = lane >> 4;

  // XCD-bijective block swizzle (256 wgs, 256 % 8 == 0)
  int wg = blockIdx.x + gridDim.x * blockIdx.y;
  wg = ((wg & 7) << 5) | (wg >> 3);
  const int bm = wg >> 2, bn = wg & 3;

  f32x4 acc[8][4];
#pragma unroll
  for (int i = 0; i < 8; ++i)
#pragma unroll
    for (int j = 0; j < 4; ++j) acc[i][j] = (f32x4){0.f, 0.f, 0.f, 0.f};

  // staging geometry: thread t covers chunk (t&7) of row (l*64 + (t>>3))
  const int rbase = t >> 3;
  const int swz_st = ((t & 7) ^ ((t >> 3) & 7)) << 3;    // swizzle (elems)
  const unsigned short* gB[4];
  const AT* gAf[4];
  int wrA[4];
#pragma unroll
  for (int l = 0; l < 4; ++l) {
    const int r = l * 64 + rbase;
    gB[l] = W + (size_t)(bn * 256 + r) * Dd + swz_st;     // pre-swizzled src
    if constexpr (AF32) {
      gAf[l] = A + (size_t)(bm * 256 + r) * Dd + ((t & 7) << 3);  // linear src
      wrA[l] = r * 64 + swz_st;                           // swizzled LDS dst
    } else {
      gAf[l] = A + (size_t)(bm * 256 + r) * Dd + swz_st;  // pre-swizzled src
    }
  }
  const int dstoff = wave * 512;                          // HW adds lane*16B

  // ds_read geometry (swizzled)
  const int rowA0 = wm * 128 + fr;
  const int rowB0 = wn * 64 + fr;
  const int swz_rd = (fq * 8) ^ ((fr & 7) << 3);

  // ---- prologue: stage tile 0 -> buf0 ----
  if constexpr (AF32) {
    float4 p0[4], p1[4];
#pragma unroll
    for (int l = 0; l < 4; ++l) {
      p0[l] = *(const float4*)(gAf[l]);
      p1[l] = *(const float4*)(gAf[l] + 4);
    }
#pragma unroll
    for (int l = 0; l < 4; ++l) GLOAD(lds + 16384 + l * 4096 + dstoff, gB[l]);
    asm volatile("s_waitcnt vmcnt(4)" ::: "memory");      // drain A, keep B(0)
#pragma unroll
    for (int l = 0; l < 4; ++l) {
      int4 w;
      w.x = cvt2(p0[l].x, p0[l].y); w.y = cvt2(p0[l].z, p0[l].w);
      w.z = cvt2(p1[l].x, p1[l].y); w.w = cvt2(p1[l].z, p1[l].w);
      *(int4*)(lds + wrA[l]) = w;
    }
    asm volatile("s_waitcnt lgkmcnt(0)" ::: "memory");
    __builtin_amdgcn_sched_barrier(0);
  } else {
#pragma unroll
    for (int l = 0; l < 4; ++l) {
      GLOAD(lds + l * 4096 + dstoff, gAf[l]);
      GLOAD(lds + 16384 + l * 4096 + dstoff, gB[l]);
    }
  }

  for (int tt = 0; tt < 16; ++tt) {
    unsigned short* bufA = lds + (tt & 1) * 32768;
    unsigned short* bufB = bufA + 16384;
    unsigned short* nA = lds + ((tt & 1) ^ 1) * 32768;
    unsigned short* nB = nA + 16384;
    const int kpre = (tt < 15 ? tt + 1 : 15) * 64;  // clamp: harmless re-stage

    float4 a0[4], a1[4];
    if constexpr (AF32) {
#pragma unroll
      for (int l = 0; l < 4; ++l) {
        a0[l] = *(const float4*)(gAf[l] + kpre);
        a1[l] = *(const float4*)(gAf[l] + kpre + 4);
      }
#pragma unroll
      for (int l = 0; l < 4; ++l) GLOAD(nB + l * 4096 + dstoff, gB[l] + kpre);
      // drain tile-t B GLOADs (4 oldest); 8 A-loads + 4 B-GLOADs stay
      asm volatile("s_waitcnt vmcnt(12)" ::: "memory");
    } else {
#pragma unroll
      for (int l = 0; l < 4; ++l) {
        GLOAD(nA + l * 4096 + dstoff, gAf[l] + kpre);
        GLOAD(nB + l * 4096 + dstoff, gB[l] + kpre);
      }
      // drain tile-t's 8 GLOADs; tile-(t+1)'s 8 stay in flight
      asm volatile("s_waitcnt vmcnt(8)" ::: "memory");
    }
    __builtin_amdgcn_s_barrier();
    PHASE(0, 0)
    __builtin_amdgcn_s_barrier();
    PHASE(0, 1)
    __builtin_amdgcn_s_barrier();
    PHASE(1, 0)
    __builtin_amdgcn_s_barrier();
    PHASE(1, 1)
    if constexpr (AF32) {
      asm volatile("s_waitcnt vmcnt(4)" ::: "memory");    // drain A regs, keep B
#pragma unroll
      for (int l = 0; l < 4; ++l) {
        int4 w;
        w.x = cvt2(a0[l].x, a0[l].y); w.y = cvt2(a0[l].z, a0[l].w);
        w.z = cvt2(a1[l].x, a1[l].y); w.w = cvt2(a1[l].z, a1[l].w);
        *(int4*)(nA + wrA[l]) = w;
      }
      asm volatile("s_waitcnt lgkmcnt(0)" ::: "memory");
      __builtin_amdgcn_sched_barrier(0);
    }
    __builtin_amdgcn_s_barrier();
  }

  // epilogue: C/D layout col=lane&15, row=(lane>>4)*4+reg
  const size_t row0 = (size_t)bm * 256 + wm * 128 + fq * 4;
  const int col0 = bn * 256 + wn * 64 + fr;
#pragma unroll
  for (int mi = 0; mi < 8; ++mi) {
#pragma unroll
    for (int ni = 0; ni < 4; ++ni) {
      const int col = col0 + ni * 16;
      const float bvl = bias[col];
#pragma unroll
      for (int r = 0; r < 4; ++r) {
        const size_t row = row0 + mi * 16 + r;
        float vv = acc[mi][ni][r] + bvl;
        if (ACT) vv = (vv > 0.f) ? (vv + 1.f) : __expf(vv);   // elu(x)+1
        if constexpr (sizeof(OutT) == 2)
          ((unsigned short*)C)[row * Dd + col] = f2bf(vv);
        else
          ((float*)C)[row * Dd + col] = vv;
      }
    }
  }
}

// ------------- KV partial: per (b,h,chunk) block, 256 rows ----------------
// part[bx][m*64+d] = sum_n V[n,m]*K[n,d];  part[bx][4096+d] = sum_n K[n,d]
__global__ __launch_bounds__(256) void kv_partial(
    const unsigned short* __restrict__ Kf, const unsigned short* __restrict__ Vf,
    float* __restrict__ part) {
  const int bx = blockIdx.x;            // b*H*NCH + h*NCH + chunk
  const int chunk = bx % NCH;
  const int bh = bx / NCH;
  const int h = bh % Hh, b = bh / Hh;
  const int t = threadIdx.x;
  const int tm = t >> 4, td = t & 15;
  __shared__ float sK[8][64];
  __shared__ float sV[8][64];
  float acc[4][4] = {{0.f}};
  float ksr[4] = {0.f, 0.f, 0.f, 0.f};

  const int which = t >> 7;             // 0: K, 1: V
  const int idx = t & 127;
  const int rr = idx >> 4;              // 0..7
  const int dpos = (idx & 15) << 2;     // 0..60
  const int colbase = h * DKk;
  const int rows = Ss / NCH;            // 256

  for (int n0 = 0; n0 < rows; n0 += 8) {
    const int gr = b * Ss + chunk * rows + n0 + rr;
    const unsigned short* src = which ? Vf : Kf;
    ushort4 raw = *(const ushort4*)&src[(size_t)gr * Dd + colbase + dpos];
    __syncthreads();
    float* dst = which ? &sV[rr][dpos] : &sK[rr][dpos];
    dst[0] = bf2f(raw.x); dst[1] = bf2f(raw.y);
    dst[2] = bf2f(raw.z); dst[3] = bf2f(raw.w);
    __syncthreads();
#pragma unroll
    for (int r = 0; r < 8; ++r) {
      float kv[4], vv[4];
#pragma unroll
      for (int j = 0; j < 4; ++j) kv[j] = sK[r][td * 4 + j];
#pragma unroll
      for (int i = 0; i < 4; ++i) vv[i] = sV[r][tm * 4 + i];
#pragma unroll
      for (int i = 0; i < 4; ++i)
#pragma unroll
        for (int j = 0; j < 4; ++j)
          acc[i][j] = fmaf(vv[i], kv[j], acc[i][j]);
      if (tm == 0) {
#pragma unroll
        for (int j = 0; j < 4; ++j) ksr[j] += kv[j];
      }
    }
  }

  float* p = part + (size_t)bx * 4160;
#pragma unroll
  for (int i = 0; i < 4; ++i)
#pragma unroll
    for (int j = 0; j < 4; ++j)
      p[(tm * 4 + i) * 64 + td * 4 + j] = acc[i][j];
  if (tm == 0) {
#pragma unroll
    for (int j = 0; j < 4; ++j) p[4096 + td * 4 + j] = ksr[j];
  }
}

// ------------- KV reduce: sum NCH partials per head ----------------
__global__ __launch_bounds__(256) void kv_reduce(
    const float* __restrict__ part, float* __restrict__ KV,
    float* __restrict__ Ksum) {
  const int bh = blockIdx.x;
  for (int e = threadIdx.x; e < 4160; e += 256) {
    float s = 0.f;
#pragma unroll
    for (int c = 0; c < NCH; ++c)
      s += part[((size_t)bh * NCH + c) * 4160 + e];
    if (e < 4096) KV[(size_t)bh * 4096 + e] = s;
    else Ksum[bh * 64 + (e - 4096)] = s;
  }
}

// ------------- attention apply via MFMA, in place over Qf (bf16) ----------
__global__ __launch_bounds__(256) void attn_mfma(
    unsigned short* __restrict__ Qf, const float* __restrict__ KV,
    const float* __restrict__ Ksum) {
  const int bh = blockIdx.x;
  const int h = bh & (Hh - 1), b = bh >> 4;
  const int t = threadIdx.x;
  const int wave = t >> 6, lane = t & 63;
  const int fr = lane & 15, fq = lane >> 4;

  bf16x8 bfrag[4][2];
  const float* kvb = KV + (size_t)bh * 4096;
#pragma unroll
  for (int nj = 0; nj < 4; ++nj)
#pragma unroll
    for (int ks = 0; ks < 2; ++ks) {
      const float* src = kvb + (nj * 16 + fr) * 64 + ks * 32 + fq * 8;
      const float4 lo = *(const float4*)src;
      const float4 hi = *(const float4*)(src + 4);
      bf16x8 f;
      f[0] = (short)f2bf(lo.x); f[1] = (short)f2bf(lo.y);
      f[2] = (short)f2bf(lo.z); f[3] = (short)f2bf(lo.w);
      f[4] = (short)f2bf(hi.x); f[5] = (short)f2bf(hi.y);
      f[6] = (short)f2bf(hi.z); f[7] = (short)f2bf(hi.w);
      bfrag[nj][ks] = f;
    }
  bf16x8 zfrag[2];
#pragma unroll
  for (int ks = 0; ks < 2; ++ks) {
    bf16x8 f = (bf16x8){0, 0, 0, 0, 0, 0, 0, 0};
    if (fr == 0) {
      const float* src = Ksum + bh * 64 + ks * 32 + fq * 8;
      const float4 lo = *(const float4*)src;
      const float4 hi = *(const float4*)(src + 4);
      f[0] = (short)f2bf(lo.x); f[1] = (short)f2bf(lo.y);
      f[2] = (short)f2bf(lo.z); f[3] = (short)f2bf(lo.w);
      f[4] = (short)f2bf(hi.x); f[5] = (short)f2bf(hi.y);
      f[6] = (short)f2bf(hi.z); f[7] = (short)f2bf(hi.w);
    }
    zfrag[ks] = f;
  }

  const size_t row0 = (size_t)b * Ss + (size_t)blockIdx.y * 256 + wave * 64;
  unsigned short* qbase = Qf + row0 * Dd + h * DKk;
  bf16x8 afrag[4][2];
#pragma unroll
  for (int mi = 0; mi < 4; ++mi)
#pragma unroll
    for (int ks = 0; ks < 2; ++ks)
      afrag[mi][ks] =
          *(const bf16x8*)(qbase + (size_t)(mi * 16 + fr) * Dd + ks * 32 + fq * 8);

  f32x4 acc[4][4], zacc[4];
#pragma unroll
  for (int mi = 0; mi < 4; ++mi) {
    zacc[mi] = (f32x4){0.f, 0.f, 0.f, 0.f};
#pragma unroll
    for (int nj = 0; nj < 4; ++nj) acc[mi][nj] = (f32x4){0.f, 0.f, 0.f, 0.f};
  }
#pragma unroll
  for (int mi = 0; mi < 4; ++mi)
#pragma unroll
    for (int ks = 0; ks < 2; ++ks) {
      zacc[mi] = __builtin_amdgcn_mfma_f32_16x16x32_bf16(
          afrag[mi][ks], zfrag[ks], zacc[mi], 0, 0, 0);
#pragma unroll
      for (int nj = 0; nj < 4; ++nj)
        acc[mi][nj] = __builtin_amdgcn_mfma_f32_16x16x32_bf16(
            afrag[mi][ks], bfrag[nj][ks], acc[mi][nj], 0, 0, 0);
    }

#pragma unroll
  for (int mi = 0; mi < 4; ++mi)
#pragma unroll
    for (int r = 0; r < 4; ++r) {
      const float zv = __shfl(zacc[mi][r], lane & 48) + 1e-6f;
      const float rz = 1.0f / zv;
      const size_t ro = (size_t)(mi * 16 + fq * 4 + r) * Dd;
#pragma unroll
      for (int nj = 0; nj < 4; ++nj)
        qbase[ro + nj * 16 + fr] = f2bf(acc[mi][nj][r] * rz);
    }
}

// ---------------------------------------------------------------------------
extern "C" void kernel_launch(void* const* d_in, const int* in_sizes, int n_in,
                              void* d_out, int out_size, void* d_ws, size_t ws_size,
                              hipStream_t stream) {
  const float* q  = (const float*)d_in[0];
  const float* k  = (const float*)d_in[1];
  const float* v  = (const float*)d_in[2];
  const float* Wq = (const float*)d_in[3];
  const float* bq = (const float*)d_in[4];
  const float* Wk = (const float*)d_in[5];
  const float* bk = (const float*)d_in[6];
  const float* Wv = (const float*)d_in[7];
  const float* bv = (const float*)d_in[8];
  const float* Wo = (const float*)d_in[9];
  const float* bo = (const float*)d_in[10];
  float* out = (float*)d_out;

  // workspace layout (bf16 stored as ushort)
  unsigned short* Kf  = (unsigned short*)d_ws;          // K feats, later Q feats
  unsigned short* Vf  = Kf  + (size_t)Mm * Dd;          // V feats
  unsigned short* Wqb = Vf  + (size_t)Mm * Dd;
  unsigned short* Wkb = Wqb + (size_t)Dd * Dd;
  unsigned short* Wvb = Wkb + (size_t)Dd * Dd;
  unsigned short* Wob = Wvb + (size_t)Dd * Dd;
  float* KV   = (float*)(Wob + (size_t)Dd * Dd);        // 64*4096 floats
  float* Ksum = KV + (size_t)Bb * Hh * DKk * DKk;       // 4096 floats
  float* part = Ksum + Bb * Hh * DKk;                   // 64*16*4160 floats

  dim3 gg(Dd / 256, Mm / 256);   // (4, 64) = 256 wgs

  // weights -> bf16 (tiny; weights are re-read 64x per GEMM, so pre-convert)
  cvt_f32_bf16<<<dim3(1024, 4), 256, 0, stream>>>(Wq, Wk, Wv, Wo, Wqb, Wkb, Wvb, Wob,
                                                  (Dd * Dd) / 4);
  // projections with fused fp32->bf16 A-staging
  gemm256<1, float, unsigned short><<<gg, 512, 0, stream>>>(k, Wkb, bk, Kf);
  gemm256<0, float, unsigned short><<<gg, 512, 0, stream>>>(v, Wvb, bv, Vf);
  kv_partial<<<Bb * Hh * NCH, 256, 0, stream>>>(Kf, Vf, part);
  kv_reduce<<<Bb * Hh, 256, 0, stream>>>(part, KV, Ksum);
  gemm256<1, float, unsigned short><<<gg, 512, 0, stream>>>(q, Wqb, bq, Kf);  // Qf
  attn_mfma<<<dim3(Bb * Hh, Ss / 256), 256, 0, stream>>>(Kf, KV, Ksum);
  gemm256<0, unsigned short, float><<<gg, 512, 0, stream>>>(Kf, Wob, bo, out);
}

// Round 7
// 289.846 us; speedup vs baseline: 6.4271x; 1.0185x over previous
//
#include <hip/hip_runtime.h>
#include <math.h>

// Problem constants
#define Bb 4
#define Ss 4096
#define Dd 1024
#define Hh 16
#define DKk 64
#define Mm (Bb * Ss)          // 16384 rows
#define NCH 16                // n-chunks per head for KV partial reduction

typedef __attribute__((ext_vector_type(8))) short bf16x8;
typedef __attribute__((ext_vector_type(4))) float f32x4;

__device__ __forceinline__ unsigned short f2bf(float f) {
  unsigned u = __float_as_uint(f);
  u += 0x7FFFu + ((u >> 16) & 1u);          // round-to-nearest-even
  return (unsigned short)(u >> 16);
}
__device__ __forceinline__ float bf2f(unsigned short s) {
  return __uint_as_float(((unsigned)s) << 16);
}
__device__ __forceinline__ unsigned cvt2(float lo, float hi) {
  unsigned r;
  asm("v_cvt_pk_bf16_f32 %0, %1, %2" : "=v"(r) : "v"(lo), "v"(hi));
  return r;   // low 16 = bf16(lo), high 16 = bf16(hi), RNE
}

#define GLOAD(dst, src)                                                     \
  __builtin_amdgcn_global_load_lds(                                         \
      (const __attribute__((address_space(1))) void*)(src),                 \
      (__attribute__((address_space(3))) void*)(dst), 16, 0, 0)

// ---------------- fp32 -> bf16: weights (small, 4 tensors) -----------------
__global__ __launch_bounds__(256) void cvt_f32_bf16(
    const float* __restrict__ s0, const float* __restrict__ s1,
    const float* __restrict__ s2, const float* __restrict__ s3,
    unsigned short* __restrict__ d0, unsigned short* __restrict__ d1,
    unsigned short* __restrict__ d2, unsigned short* __restrict__ d3, int n4) {
  const float* s; unsigned short* d;
  switch (blockIdx.y) {
    case 0:  s = s0; d = d0; break;
    case 1:  s = s1; d = d1; break;
    case 2:  s = s2; d = d2; break;
    default: s = s3; d = d3; break;
  }
  const int i = blockIdx.x * 256 + threadIdx.x;
  if (i < n4) {
    float4 v = ((const float4*)s)[i];
    ushort4 o;
    o.x = f2bf(v.x); o.y = f2bf(v.y); o.z = f2bf(v.z); o.w = f2bf(v.w);
    ((ushort4*)d)[i] = o;
  }
}

// ---------------- fp32 -> bf16: activations (grid-stride, 32B/iter) --------
__global__ __launch_bounds__(256) void cvt_pk_f32_bf16(
    const float* __restrict__ s0, const float* __restrict__ s1,
    unsigned short* __restrict__ d0, unsigned short* __restrict__ d1,
    int n8) {
  const float* s = blockIdx.y ? s1 : s0;
  unsigned short* d = blockIdx.y ? d1 : d0;
  for (long i = (long)blockIdx.x * 256 + threadIdx.x; i < n8;
       i += (long)gridDim.x * 256) {
    float4 a = ((const float4*)s)[2 * i];
    float4 b = ((const float4*)s)[2 * i + 1];
    int4 w;
    w.x = cvt2(a.x, a.y); w.y = cvt2(a.z, a.w);
    w.z = cvt2(b.x, b.y); w.w = cvt2(b.z, b.w);
    ((int4*)d)[i] = w;
  }
}

// ---------------- 256x256 deep-pipelined bf16 MFMA GEMM --------------------
// C = act(A[M,1024] @ W[1024,1024]^T + bias). BK=64, 512 thr / 8 waves (2x4).
// 4 phases per K-tile; staging of tile t+1 at P0 (A) / P1 (B) via
// global_load_lds; counted s_waitcnt vmcnt(4) at P0 only (never 0 in-loop).
// T2 XOR swizzle: inverse pre-applied to the GLOBAL source, linear LDS dest.
#define PHASE(mh, nh)                                                        \
  {                                                                          \
    bf16x8 af[4][2], bv_[2][2];                                              \
    _Pragma("unroll") for (int mi = 0; mi < 4; ++mi)                         \
      _Pragma("unroll") for (int ks = 0; ks < 2; ++ks)                       \
        af[mi][ks] = *(const bf16x8*)(bufA +                                 \
            (rowA0 + (mh) * 64 + mi * 16) * 64 + (swz_rd ^ (ks * 32)));      \
    _Pragma("unroll") for (int ni = 0; ni < 2; ++ni)                         \
      _Pragma("unroll") for (int ks = 0; ks < 2; ++ks)                       \
        bv_[ni][ks] = *(const bf16x8*)(bufB +                                \
            (rowB0 + (nh) * 32 + ni * 16) * 64 + (swz_rd ^ (ks * 32)));      \
    __builtin_amdgcn_s_setprio(1);                                           \
    _Pragma("unroll") for (int mi = 0; mi < 4; ++mi)                         \
      _Pragma("unroll") for (int ni = 0; ni < 2; ++ni)                       \
        _Pragma("unroll") for (int ks = 0; ks < 2; ++ks)                     \
          acc[(mh) * 4 + mi][(nh) * 2 + ni] =                                \
              __builtin_amdgcn_mfma_f32_16x16x32_bf16(                       \
                  af[mi][ks], bv_[ni][ks],                                   \
                  acc[(mh) * 4 + mi][(nh) * 2 + ni], 0, 0, 0);               \
    __builtin_amdgcn_s_setprio(0);                                           \
  }

template <typename OutT>
__device__ __forceinline__ void gemm256_body(
    const unsigned short* __restrict__ A,   // [M,1024] bf16 bits
    const unsigned short* __restrict__ W,   // [1024,1024] bf16 bits (N,K)
    const float* __restrict__ bias,
    OutT* __restrict__ C, const int act, const int wg_in,
    unsigned short* lds) {
  const int t = threadIdx.x;
  const int wave = t >> 6, lane = t & 63;
  const int wm = wave >> 2, wn = wave & 3;
  const int fr = lane & 15, fq = lane >> 4;

  // XCD-bijective block swizzle (256 wgs per GEMM, 256 % 8 == 0)
  const int wg = ((wg_in & 7) << 5) | (wg_in >> 3);
  const int bm = wg >> 2, bn = wg & 3;

  f32x4 acc[8][4];
#pragma unroll
  for (int i = 0; i < 8; ++i)
#pragma unroll
    for (int j = 0; j < 4; ++j) acc[i][j] = (f32x4){0.f, 0.f, 0.f, 0.f};

  // staging geometry: thread t covers LDS linear slot (l*512+t)*16B
  const int rbase = t >> 3;                              // row for l=0
  const int swz_st = ((t & 7) ^ ((t >> 3) & 7)) << 3;    // inverse swizzle
  const unsigned short* gA[4];
  const unsigned short* gB[4];
#pragma unroll
  for (int l = 0; l < 4; ++l) {
    const int r = l * 64 + rbase;
    gA[l] = A + (size_t)(bm * 256 + r) * Dd + swz_st;
    gB[l] = W + (size_t)(bn * 256 + r) * Dd + swz_st;
  }
  const int dstoff = wave * 512;                         // HW adds lane*16B

  // ds_read geometry (swizzled)
  const int rowA0 = wm * 128 + fr;
  const int rowB0 = wn * 64 + fr;
  const int swz_rd = (fq * 8) ^ ((fr & 7) << 3);

  // prologue: stage tile 0 -> buf0
#pragma unroll
  for (int l = 0; l < 4; ++l) {
    GLOAD(lds + l * 4096 + dstoff, gA[l]);
    GLOAD(lds + 16384 + l * 4096 + dstoff, gB[l]);
  }

  for (int tt = 0; tt < 16; ++tt) {
    unsigned short* bufA = lds + (tt & 1) * 32768;
    unsigned short* bufB = bufA + 16384;
    unsigned short* nA = lds + ((tt & 1) ^ 1) * 32768;
    unsigned short* nB = nA + 16384;
    const int kpre = (tt < 15 ? tt + 1 : 15) * 64;  // clamp: harmless re-stage

    // P0: issue next-A, drain current tile (counted), compute quadrant (0,0)
#pragma unroll
    for (int l = 0; l < 4; ++l) GLOAD(nA + l * 4096 + dstoff, gA[l] + kpre);
    asm volatile("s_waitcnt vmcnt(4)" ::: "memory");
    __builtin_amdgcn_s_barrier();
    PHASE(0, 0)
    __builtin_amdgcn_s_barrier();
    // P1: issue next-B, compute quadrant (0,1)
#pragma unroll
    for (int l = 0; l < 4; ++l) GLOAD(nB + l * 4096 + dstoff, gB[l] + kpre);
    PHASE(0, 1)
    __builtin_amdgcn_s_barrier();
    PHASE(1, 0)
    __builtin_amdgcn_s_barrier();
    PHASE(1, 1)
    __builtin_amdgcn_s_barrier();
  }

  // epilogue: C/D layout col=lane&15, row=(lane>>4)*4+reg
  const size_t row0 = (size_t)bm * 256 + wm * 128 + fq * 4;
  const int col0 = bn * 256 + wn * 64 + fr;
#pragma unroll
  for (int mi = 0; mi < 8; ++mi) {
#pragma unroll
    for (int ni = 0; ni < 4; ++ni) {
      const int col = col0 + ni * 16;
      const float bvl = bias[col];
#pragma unroll
      for (int r = 0; r < 4; ++r) {
        const size_t row = row0 + mi * 16 + r;
        float vv = acc[mi][ni][r] + bvl;
        if (act) vv = (vv > 0.f) ? (vv + 1.f) : __expf(vv);   // elu(x)+1
        if constexpr (sizeof(OutT) == 2)
          ((unsigned short*)C)[row * Dd + col] = f2bf(vv);
        else
          ((float*)C)[row * Dd + col] = vv;
      }
    }
  }
}

template <int ACT, typename OutT>
__global__ __launch_bounds__(512, 2) void gemm256(
    const unsigned short* __restrict__ A, const unsigned short* __restrict__ W,
    const float* __restrict__ bias, OutT* __restrict__ C) {
  __shared__ __align__(16) unsigned short lds[2 * 32768];  // 128 KiB
  gemm256_body<OutT>(A, W, bias, C, ACT,
                     blockIdx.x + gridDim.x * blockIdx.y, lds);
}

// k-projection (act=1) and v-projection (act=0) in one launch via z-mux
__global__ __launch_bounds__(512, 2) void gemm256_kv(
    const unsigned short* __restrict__ A0, const unsigned short* __restrict__ W0,
    const float* __restrict__ b0, unsigned short* __restrict__ C0,
    const unsigned short* __restrict__ A1, const unsigned short* __restrict__ W1,
    const float* __restrict__ b1, unsigned short* __restrict__ C1) {
  __shared__ __align__(16) unsigned short lds[2 * 32768];
  const int wg = blockIdx.x + gridDim.x * blockIdx.y;
  if (blockIdx.z == 0)
    gemm256_body<unsigned short>(A0, W0, b0, C0, 1, wg, lds);
  else
    gemm256_body<unsigned short>(A1, W1, b1, C1, 0, wg, lds);
}

// ------------- KV partial: per (b,h,chunk) block, 256 rows ----------------
// part[bx][m*64+d] = sum_n V[n,m]*K[n,d];  part[bx][4096+d] = sum_n K[n,d]
__global__ __launch_bounds__(256) void kv_partial(
    const unsigned short* __restrict__ Kf, const unsigned short* __restrict__ Vf,
    float* __restrict__ part) {
  const int bx = blockIdx.x;            // b*H*NCH + h*NCH + chunk
  const int chunk = bx % NCH;
  const int bh = bx / NCH;
  const int h = bh % Hh, b = bh / Hh;
  const int t = threadIdx.x;
  const int tm = t >> 4, td = t & 15;
  __shared__ float sK[8][64];
  __shared__ float sV[8][64];
  float acc[4][4] = {{0.f}};
  float ksr[4] = {0.f, 0.f, 0.f, 0.f};

  const int which = t >> 7;             // 0: K, 1: V
  const int idx = t & 127;
  const int rr = idx >> 4;              // 0..7
  const int dpos = (idx & 15) << 2;     // 0..60
  const int colbase = h * DKk;
  const int rows = Ss / NCH;            // 256

  for (int n0 = 0; n0 < rows; n0 += 8) {
    const int gr = b * Ss + chunk * rows + n0 + rr;
    const unsigned short* src = which ? Vf : Kf;
    ushort4 raw = *(const ushort4*)&src[(size_t)gr * Dd + colbase + dpos];
    __syncthreads();
    float* dst = which ? &sV[rr][dpos] : &sK[rr][dpos];
    dst[0] = bf2f(raw.x); dst[1] = bf2f(raw.y);
    dst[2] = bf2f(raw.z); dst[3] = bf2f(raw.w);
    __syncthreads();
#pragma unroll
    for (int r = 0; r < 8; ++r) {
      float kv[4], vv[4];
#pragma unroll
      for (int j = 0; j < 4; ++j) kv[j] = sK[r][td * 4 + j];
#pragma unroll
      for (int i = 0; i < 4; ++i) vv[i] = sV[r][tm * 4 + i];
#pragma unroll
      for (int i = 0; i < 4; ++i)
#pragma unroll
        for (int j = 0; j < 4; ++j)
          acc[i][j] = fmaf(vv[i], kv[j], acc[i][j]);
      if (tm == 0) {
#pragma unroll
        for (int j = 0; j < 4; ++j) ksr[j] += kv[j];
      }
    }
  }

  float* p = part + (size_t)bx * 4160;
#pragma unroll
  for (int i = 0; i < 4; ++i)
#pragma unroll
    for (int j = 0; j < 4; ++j)
      p[(tm * 4 + i) * 64 + td * 4 + j] = acc[i][j];
  if (tm == 0) {
#pragma unroll
    for (int j = 0; j < 4; ++j) p[4096 + td * 4 + j] = ksr[j];
  }
}

// ------------- KV reduce: sum NCH partials per head ----------------
__global__ __launch_bounds__(256) void kv_reduce(
    const float* __restrict__ part, float* __restrict__ KV,
    float* __restrict__ Ksum) {
  const int bh = blockIdx.x;
  for (int e = threadIdx.x; e < 4160; e += 256) {
    float s = 0.f;
#pragma unroll
    for (int c = 0; c < NCH; ++c)
      s += part[((size_t)bh * NCH + c) * 4160 + e];
    if (e < 4096) KV[(size_t)bh * 4096 + e] = s;
    else Ksum[bh * 64 + (e - 4096)] = s;
  }
}

// ------------- attention apply via MFMA, in place over Qf (bf16) ----------
__global__ __launch_bounds__(256) void attn_mfma(
    unsigned short* __restrict__ Qf, const float* __restrict__ KV,
    const float* __restrict__ Ksum) {
  const int bh = blockIdx.x;
  const int h = bh & (Hh - 1), b = bh >> 4;
  const int t = threadIdx.x;
  const int wave = t >> 6, lane = t & 63;
  const int fr = lane & 15, fq = lane >> 4;

  bf16x8 bfrag[4][2];
  const float* kvb = KV + (size_t)bh * 4096;
#pragma unroll
  for (int nj = 0; nj < 4; ++nj)
#pragma unroll
    for (int ks = 0; ks < 2; ++ks) {
      const float* src = kvb + (nj * 16 + fr) * 64 + ks * 32 + fq * 8;
      const float4 lo = *(const float4*)src;
      const float4 hi = *(const float4*)(src + 4);
      bf16x8 f;
      f[0] = (short)f2bf(lo.x); f[1] = (short)f2bf(lo.y);
      f[2] = (short)f2bf(lo.z); f[3] = (short)f2bf(lo.w);
      f[4] = (short)f2bf(hi.x); f[5] = (short)f2bf(hi.y);
      f[6] = (short)f2bf(hi.z); f[7] = (short)f2bf(hi.w);
      bfrag[nj][ks] = f;
    }
  bf16x8 zfrag[2];
#pragma unroll
  for (int ks = 0; ks < 2; ++ks) {
    bf16x8 f = (bf16x8){0, 0, 0, 0, 0, 0, 0, 0};
    if (fr == 0) {
      const float* src = Ksum + bh * 64 + ks * 32 + fq * 8;
      const float4 lo = *(const float4*)src;
      const float4 hi = *(const float4*)(src + 4);
      f[0] = (short)f2bf(lo.x); f[1] = (short)f2bf(lo.y);
      f[2] = (short)f2bf(lo.z); f[3] = (short)f2bf(lo.w);
      f[4] = (short)f2bf(hi.x); f[5] = (short)f2bf(hi.y);
      f[6] = (short)f2bf(hi.z); f[7] = (short)f2bf(hi.w);
    }
    zfrag[ks] = f;
  }

  const size_t row0 = (size_t)b * Ss + (size_t)blockIdx.y * 256 + wave * 64;
  unsigned short* qbase = Qf + row0 * Dd + h * DKk;
  bf16x8 afrag[4][2];
#pragma unroll
  for (int mi = 0; mi < 4; ++mi)
#pragma unroll
    for (int ks = 0; ks < 2; ++ks)
      afrag[mi][ks] =
          *(const bf16x8*)(qbase + (size_t)(mi * 16 + fr) * Dd + ks * 32 + fq * 8);

  f32x4 acc[4][4], zacc[4];
#pragma unroll
  for (int mi = 0; mi < 4; ++mi) {
    zacc[mi] = (f32x4){0.f, 0.f, 0.f, 0.f};
#pragma unroll
    for (int nj = 0; nj < 4; ++nj) acc[mi][nj] = (f32x4){0.f, 0.f, 0.f, 0.f};
  }
#pragma unroll
  for (int mi = 0; mi < 4; ++mi)
#pragma unroll
    for (int ks = 0; ks < 2; ++ks) {
      zacc[mi] = __builtin_amdgcn_mfma_f32_16x16x32_bf16(
          afrag[mi][ks], zfrag[ks], zacc[mi], 0, 0, 0);
#pragma unroll
      for (int nj = 0; nj < 4; ++nj)
        acc[mi][nj] = __builtin_amdgcn_mfma_f32_16x16x32_bf16(
            afrag[mi][ks], bfrag[nj][ks], acc[mi][nj], 0, 0, 0);
    }

#pragma unroll
  for (int mi = 0; mi < 4; ++mi)
#pragma unroll
    for (int r = 0; r < 4; ++r) {
      const float zv = __shfl(zacc[mi][r], lane & 48) + 1e-6f;
      const float rz = 1.0f / zv;
      const size_t ro = (size_t)(mi * 16 + fq * 4 + r) * Dd;
#pragma unroll
      for (int nj = 0; nj < 4; ++nj)
        qbase[ro + nj * 16 + fr] = f2bf(acc[mi][nj][r] * rz);
    }
}

// ---------------------------------------------------------------------------
extern "C" void kernel_launch(void* const* d_in, const int* in_sizes, int n_in,
                              void* d_out, int out_size, void* d_ws, size_t ws_size,
                              hipStream_t stream) {
  const float* q  = (const float*)d_in[0];
  const float* k  = (const float*)d_in[1];
  const float* v  = (const float*)d_in[2];
  const float* Wq = (const float*)d_in[3];
  const float* bq = (const float*)d_in[4];
  const float* Wk = (const float*)d_in[5];
  const float* bk = (const float*)d_in[6];
  const float* Wv = (const float*)d_in[7];
  const float* bv = (const float*)d_in[8];
  const float* Wo = (const float*)d_in[9];
  const float* bo = (const float*)d_in[10];
  float* out = (float*)d_out;

  // workspace layout (bf16 stored as ushort)
  unsigned short* kb  = (unsigned short*)d_ws;          // k bf16; later part; later q bf16
  unsigned short* vb  = kb + (size_t)Mm * Dd;           // v bf16
  unsigned short* Kf  = vb + (size_t)Mm * Dd;           // K feats, later Q feats
  unsigned short* Vf  = Kf + (size_t)Mm * Dd;           // V feats
  unsigned short* Wqb = Vf + (size_t)Mm * Dd;
  unsigned short* Wkb = Wqb + (size_t)Dd * Dd;
  unsigned short* Wvb = Wkb + (size_t)Dd * Dd;
  unsigned short* Wob = Wvb + (size_t)Dd * Dd;
  float* KV   = (float*)(Wob + (size_t)Dd * Dd);        // 64*4096 floats
  float* Ksum = KV + (size_t)Bb * Hh * DKk * DKk;       // 4096 floats
  float* part = (float*)kb;                             // 17 MB, lifetime: steps 4-5

  dim3 gg(Dd / 256, Mm / 256);          // (4, 64) = 256 wgs
  dim3 ggkv(Dd / 256, Mm / 256, 2);     // k and v GEMMs fused
  const int n8 = (Mm * Dd) / 8;         // activations: 16M elems -> 2M int4s

  // 1) weights -> bf16
  cvt_f32_bf16<<<dim3(1024, 4), 256, 0, stream>>>(Wq, Wk, Wv, Wo, Wqb, Wkb, Wvb, Wob,
                                                  (Dd * Dd) / 4);
  // 2) k, v -> bf16 (grid-stride)
  cvt_pk_f32_bf16<<<dim3(2048, 2), 256, 0, stream>>>(k, v, kb, vb, n8);
  // 3) K and V projections (one launch)
  gemm256_kv<<<ggkv, 512, 0, stream>>>(kb, Wkb, bk, Kf, vb, Wvb, bv, Vf);
  // 4) KV partial sums (part overwrites kb region; kb dead after step 3)
  kv_partial<<<Bb * Hh * NCH, 256, 0, stream>>>(Kf, Vf, part);
  // 5) reduce
  kv_reduce<<<Bb * Hh, 256, 0, stream>>>(part, KV, Ksum);
  // 6) q -> bf16 (kb region free again after step 5)
  cvt_pk_f32_bf16<<<dim3(2048, 1), 256, 0, stream>>>(q, nullptr, kb, nullptr, n8);
  // 7) Q projection -> Kf (free after step 4)
  gemm256<1, unsigned short><<<gg, 512, 0, stream>>>(kb, Wqb, bq, Kf);
  // 8) attention apply in-place
  attn_mfma<<<dim3(Bb * Hh, Ss / 256), 256, 0, stream>>>(Kf, KV, Ksum);
  // 9) output projection
  gemm256<0, float><<<gg, 512, 0, stream>>>(Kf, Wob, bo, out);
}